// Round 12
// baseline (779.580 us; speedup 1.0000x reference)
//
#include <hip/hip_runtime.h>
#include <hip/hip_bf16.h>
#include <hip/hip_cooperative_groups.h>
namespace cg = cooperative_groups;

// Problem constants
#define Bc 2
#define Nc 6
#define Cc 128
#define Hc 16
#define Wc 44
#define Dc 64
#define HWc (Hc*Wc)          // 704
#define BNc (Bc*Nc)          // 12
#define NRAY (Nc*HWc)        // 4224
#define NPTS (Bc*Nc*Dc*HWc)  // 540672
#define BEV_W 256
#define BEV_H 256
#define BEV_HW (BEV_W*BEV_H) // 65536
#define NSEG (Bc*BEV_HW)     // 131072
#define GT 16
#define NTILE (NSEG/GT)      // 8192
#define NSCANB (NSEG/256)    // 512 scanning blocks (fixed, independent of grid)

// ---------------- workspace layout (bytes) ----------------
#define OFF_KI    0                      // fallback only
#define OFF_DB    512                    // fallback only
#define OFF_CNT   1024                   // int cnt[NSEG]      524288
#define OFF_OFFS  (OFF_CNT  + 524288)    // int offs[NSEG]     524288
#define OFF_FILL  (OFF_OFFS + 524288)    // int fill[NSEG]     524288
#define OFF_BSUM  (OFF_FILL + 524288)    // int bsum[512]
#define OFF_ETOT  (OFF_BSUM + 2048)      // int Etot[1]
#define OFF_E8    (OFF_BSUM + 4096)      // int2 e8[NPTS]      4325376
#define OFF_FT    (OFF_E8   + 4325376)   // float ft[B][NRAY][128] 4325376
#define WS_NEED   (OFF_FT   + 4325376)   // ~9.8 MB
#define OFF_ACC   (OFF_FT   + 4325376)   // float acc[NSEG][128] 67108864
#define WS_BIG    (OFF_ACC  + 67108864)  // ~77 MB
#define OFF_FIDX  OFF_E8
#define OFF_FCNT  OFF_CNT

// ---------------------------------------------------------------------------
__device__ __forceinline__ void setup_into(int tid, const float* __restrict__ intr,
                                           const int* __restrict__ p_imgh,
                                           const int* __restrict__ p_imgw,
                                           float* Ki, float* db) {
    if (tid < Dc) {
        double v = 1.0 + (double)tid * (59.0 / 63.0);
        db[tid] = (tid == Dc - 1) ? 60.0f : (float)v;
    }
    if (tid >= BNc) return;
    double img_h = (double)p_imgh[0];
    double img_w = (double)p_imgw[0];
    double scale_x = (double)Wc / (img_w / 16.0);
    double scale_y = (double)Hc / (img_h / 16.0);
    float rs0 = (float)(16.0 / scale_x);
    float rs1 = (float)(16.0 / scale_y);
    float rs2 = 1.0f;
    const float* K = intr + tid * 9;
    float k0 = __fmul_rn(K[0], rs0), k1 = __fmul_rn(K[1], rs0), k2 = __fmul_rn(K[2], rs0);
    float k3 = __fmul_rn(K[3], rs1), k4 = __fmul_rn(K[4], rs1), k5 = __fmul_rn(K[5], rs1);
    float k6 = __fmul_rn(K[6], rs2), k7 = __fmul_rn(K[7], rs2), k8 = __fmul_rn(K[8], rs2);
    float c0 = __fsub_rn(__fmul_rn(k4,k8), __fmul_rn(k5,k7));
    float c1 = __fsub_rn(__fmul_rn(k3,k8), __fmul_rn(k5,k6));
    float c2 = __fsub_rn(__fmul_rn(k3,k7), __fmul_rn(k4,k6));
    float det = __fadd_rn(__fsub_rn(__fmul_rn(k0,c0), __fmul_rn(k1,c1)), __fmul_rn(k2,c2));
    float* o = Ki + tid * 9;
    o[0] = __fdiv_rn(c0, det);
    o[1] = __fdiv_rn(__fsub_rn(__fmul_rn(k2,k7), __fmul_rn(k1,k8)), det);
    o[2] = __fdiv_rn(__fsub_rn(__fmul_rn(k1,k5), __fmul_rn(k2,k4)), det);
    o[3] = __fdiv_rn(__fsub_rn(__fmul_rn(k5,k6), __fmul_rn(k3,k8)), det);
    o[4] = __fdiv_rn(__fsub_rn(__fmul_rn(k0,k8), __fmul_rn(k2,k6)), det);
    o[5] = __fdiv_rn(__fsub_rn(__fmul_rn(k2,k3), __fmul_rn(k0,k5)), det);
    o[6] = __fdiv_rn(c2, det);
    o[7] = __fdiv_rn(__fsub_rn(__fmul_rn(k1,k6), __fmul_rn(k0,k7)), det);
    o[8] = __fdiv_rn(__fsub_rn(__fmul_rn(k0,k4), __fmul_rn(k1,k3)), det);
}

__global__ void k_setup(const float* __restrict__ intr, const float* __restrict__ extr,
                        const int* __restrict__ p_imgh, const int* __restrict__ p_imgw,
                        float* __restrict__ Ki, float* __restrict__ db) {
    setup_into(threadIdx.x, intr, p_imgh, p_imgw, Ki, db);
}

__device__ __forceinline__ int classify_point(int gid, const float* Ki_all,
                                              const float* db, const float* extr) {
    int p   = gid % HWc;
    int tmp = gid / HWc;
    int d   = tmp % Dc;
    int bn  = tmp / Dc;
    int w = p % Wc, h = p / Wc;
    float dd = db[d];
    float ud = __fmul_rn((float)w, dd);
    float vd = __fmul_rn((float)h, dd);
    const float* Ki = Ki_all + bn * 9;
    float pcx = fmaf(Ki[2], dd, fmaf(Ki[1], vd, __fmul_rn(Ki[0], ud)));
    float pcy = fmaf(Ki[5], dd, fmaf(Ki[4], vd, __fmul_rn(Ki[3], ud)));
    float pcz = fmaf(Ki[8], dd, fmaf(Ki[7], vd, __fmul_rn(Ki[6], ud)));
    const float* E = extr + bn * 16;
    float px = __fadd_rn(fmaf(E[2],  pcz, fmaf(E[1], pcy, __fmul_rn(E[0], pcx))), E[3]);
    float py = __fadd_rn(fmaf(E[6],  pcz, fmaf(E[5], pcy, __fmul_rn(E[4], pcx))), E[7]);
    float pz = __fadd_rn(fmaf(E[10], pcz, fmaf(E[9], pcy, __fmul_rn(E[8], pcx))), E[11]);
    float fx = __fdiv_rn(__fsub_rn(px, -51.2f), 0.4f);
    float fy = __fdiv_rn(__fsub_rn(py, -51.2f), 0.4f);
    int xi = (int)fx;
    int yi = (int)fy;
    bool valid = (xi >= 0) && (xi < BEV_W) && (yi >= 0) && (yi < BEV_H)
              && (pz >= -5.0f) && (pz <= 3.0f);
    return valid ? (yi * BEV_W + xi) : -1;
}

// ===========================================================================
// COOPERATIVE fused kernel — grid-size agnostic (grid >= 512 required).
// __launch_bounds__(256, 8): full 8 blocks/CU occupancy (round-11 ran at 2
// blocks/CU -> latency-bound phases 4x slower; VGPR=44 fits the 64 cap).
// ===========================================================================
__global__ __launch_bounds__(256, 8) void k_fused(
    const float* __restrict__ intr, const float* __restrict__ extr,
    const int* __restrict__ p_imgh, const int* __restrict__ p_imgw,
    const float* __restrict__ feat, const float* __restrict__ depth,
    int* __restrict__ cnt, int* __restrict__ offs, int* __restrict__ fill,
    int* __restrict__ bsum, int2* __restrict__ e8, float* __restrict__ ft,
    float* __restrict__ acc, float* __restrict__ out)
{
    cg::grid_group grid = cg::this_grid();
    __shared__ float sKi[BNc * 9];
    __shared__ float sDb[Dc];
    __shared__ int   sB[NSCANB];       // exclusive-scanned block sums (replicated)
    __shared__ int   sEtotS;
    __shared__ float uni[Cc * 17];     // union: transpose buf / scan scratch / finish res
    __shared__ float sInv[GT];
    __shared__ int   sC[GT + 1];

    int tid = threadIdx.x;
    int bid = blockIdx.x;
    int nb  = gridDim.x;
    int gs  = nb << 8;                 // grid stride in threads

    setup_into(tid, intr, p_imgh, p_imgw, sKi, sDb);

    // ---- phase 0: zero cnt + transpose feat -> ft[b][ray][c] ----
    for (int i = bid * 256 + tid; i < NSEG; i += gs) cnt[i] = 0;
    for (int tt = bid; tt < BNc * (HWc / 16); tt += nb) {
        __syncthreads();
        int bn   = tt / (HWc / 16);
        int tile = tt % (HWc / 16);
        const float* fb = feat + (size_t)bn * Cc * HWc + tile * 16;
        for (int i = tid; i < Cc * 16; i += 256) {
            int c = i >> 4, hw = i & 15;
            uni[c * 17 + hw] = fb[c * HWc + hw];
        }
        __syncthreads();
        float* obt = ft + ((size_t)bn * HWc + tile * 16) * Cc;
        for (int i = tid; i < 16 * Cc; i += 256) {
            int r = i >> 7, ch = i & 127;
            obt[(size_t)r * Cc + ch] = uni[ch * 17 + r];
        }
    }
    grid.sync();

    // ---- phase 1: count ----
    for (int gid = bid * 256 + tid; gid < NPTS; gid += gs) {
        int cell = classify_point(gid, sKi, sDb, extr);
        if (cell >= 0)
            atomicAdd(&cnt[(gid / (Nc * Dc * HWc)) * BEV_HW + cell], 1);
    }
    grid.sync();

    // ---- phase 2A: first 512 blocks each scan 256 counts ----
    if (bid < NSCANB) {
        int* su = (int*)uni;
        int g = bid * 256 + tid;
        int v = cnt[g];
        su[tid] = v;
        __syncthreads();
        for (int st = 1; st < 256; st <<= 1) {
            int t2 = (tid >= st) ? su[tid - st] : 0;
            __syncthreads();
            su[tid] += t2;
            __syncthreads();
        }
        int e = su[tid] - v;
        offs[g] = e;
        fill[g] = e;
        if (tid == 255) bsum[bid] = su[255];
    }
    grid.sync();

    // ---- phase 2B: EVERY block scans bsum[512] into its own LDS sB ----
    {
        int* su = (int*)uni;
        int2 v2 = ((const int2*)bsum)[tid];      // 512 ints = 256 int2
        int s = v2.x + v2.y;
        __syncthreads();                          // uni reuse guard
        su[tid] = s;
        __syncthreads();
        for (int st = 1; st < 256; st <<= 1) {
            int t2 = (tid >= st) ? su[tid - st] : 0;
            __syncthreads();
            su[tid] += t2;
            __syncthreads();
        }
        int base = su[tid] - s;                  // exclusive
        sB[2 * tid]     = base;
        sB[2 * tid + 1] = base + v2.x;
        if (tid == 255) sEtotS = base + s;
        __syncthreads();
    }

    // ---- phase 3: fill packed entries {ray | seg<<13, w-bits} ----
    for (int gid = bid * 256 + tid; gid < NPTS; gid += gs) {
        int cell = classify_point(gid, sKi, sDb, extr);
        if (cell < 0) continue;
        int p  = gid % HWc;
        int bn = gid / (Dc * HWc);
        int b  = bn / Nc;
        int seg = b * BEV_HW + cell;
        int pos = atomicAdd(&fill[seg], 1) + sB[seg >> 8];
        int ray = (bn % Nc) * HWc + p;
        e8[pos] = make_int2(ray | (seg << 13), __float_as_int(depth[gid]));
    }
    grid.sync();

    // ---- phase 4: entry-parallel ownership gather -> acc[seg][128] ----
    {
        const float2* ft2 = (const float2*)ft;
        int Etot = sEtotS;
        int lane = tid & 63;
        int nw   = nb * 4;
        int wid  = bid * 4 + (tid >> 6);
        int WCH  = (Etot + nw - 1) / nw;
        int start = wid * WCH;
        if (start < Etot && WCH > 0) {
            int end = start + WCH; if (end > Etot) end = Etot;
            int k0 = 0;
            bool active = true;
            if (start > 0) {
                int segP = e8[start - 1].x >> 13;
                k0 = offs[segP] + sB[segP >> 8] + cnt[segP];
                if (k0 >= end) active = false;
            }
            if (active) {
                int segE = e8[end - 1].x >> 13;
                int kend = offs[segE] + sB[segE >> 8] + cnt[segE];
                int total = kend - k0;
                float2 a = make_float2(0.f, 0.f);
                int curc = -1;
                const int U = 8;
                int nbk = total / U;
                if (nbk > 0) {
                    int2 e[U];
                    #pragma unroll
                    for (int u = 0; u < U; u++) e[u] = e8[k0 + u];
                    for (int g = 0; g < nbk; g++) {
                        float2 f[U];
                        #pragma unroll
                        for (int u = 0; u < U; u++) {
                            int sx = e[u].x;
                            f[u] = ft2[((size_t)((sx >> 29) * NRAY) + (sx & 8191)) * 64 + lane];
                        }
                        int2 en[U];
                        if (g + 1 < nbk) {
                            #pragma unroll
                            for (int u = 0; u < U; u++) en[u] = e8[k0 + (g + 1) * U + u];
                        } else {
                            #pragma unroll
                            for (int u = 0; u < U; u++) en[u] = e[u];
                        }
                        #pragma unroll
                        for (int u = 0; u < U; u++) {
                            int sg = e[u].x >> 13;
                            if (sg != curc) {
                                if (curc >= 0) *(float2*)(acc + (size_t)curc * Cc + 2 * lane) = a;
                                curc = sg; a.x = 0.f; a.y = 0.f;
                            }
                            float ww = __int_as_float(e[u].y);
                            a.x = fmaf(ww, f[u].x, a.x);
                            a.y = fmaf(ww, f[u].y, a.y);
                        }
                        #pragma unroll
                        for (int u = 0; u < U; u++) e[u] = en[u];
                    }
                }
                for (int j = nbk * U; j < total; j++) {
                    int2 ee = e8[k0 + j];
                    int sg = ee.x >> 13;
                    if (sg != curc) {
                        if (curc >= 0) *(float2*)(acc + (size_t)curc * Cc + 2 * lane) = a;
                        curc = sg; a.x = 0.f; a.y = 0.f;
                    }
                    float ww = __int_as_float(ee.y);
                    float2 f = ft2[((size_t)((ee.x >> 29) * NRAY) + (ee.x & 8191)) * 64 + lane];
                    a.x = fmaf(ww, f.x, a.x);
                    a.y = fmaf(ww, f.y, a.y);
                }
                if (curc >= 0) *(float2*)(acc + (size_t)curc * Cc + 2 * lane) = a;
            }
        }
    }
    grid.sync();

    // ---- phase 5: finish — normalize + transpose acc -> out ----
    for (int t = bid; t < NTILE; t += nb) {
        __syncthreads();
        int seg0  = t * GT;
        int b     = seg0 >> 16;
        int cell0 = seg0 & 65535;
        if (tid < 64) {
            int n = (tid < GT) ? cnt[seg0 + tid] : 0;
            int v = n;
            #pragma unroll
            for (int d = 1; d < GT; d <<= 1) {
                int y = __shfl_up(v, d, GT);
                if ((tid & (GT - 1)) >= d) v += y;
            }
            if (tid < GT) {
                sC[tid] = n;
                sInv[tid] = __fdiv_rn(1.0f, __fadd_rn((float)n, 1e-5f));
                if (tid == GT - 1) sC[GT] = v;
            }
        }
        __syncthreads();
        float* ob = out + (size_t)b * Cc * BEV_HW + cell0;
        if (sC[GT] == 0) {
            float4 z = {0.f, 0.f, 0.f, 0.f};
            for (int i = tid; i < Cc * GT / 4; i += 256) {
                int q = i & 3, c = i >> 2;
                *(float4*)(ob + (size_t)c * BEV_HW + q * 4) = z;
            }
            continue;
        }
        {
            int g0 = tid >> 5, l32 = tid & 31;
            #pragma unroll
            for (int pass = 0; pass < 2; pass++) {
                int g = g0 + pass * 8;
                float4 v;
                if (sC[g] > 0) v = *(const float4*)(acc + (size_t)(seg0 + g) * Cc + 4 * l32);
                else           v = make_float4(0.f, 0.f, 0.f, 0.f);
                *(float4*)(&uni[g * 132 + 4 * l32]) = v;
            }
        }
        __syncthreads();
        for (int i = tid; i < Cc * GT / 4; i += 256) {
            int q = i & 3, c = i >> 2;
            float4 v;
            #pragma unroll
            for (int kk = 0; kk < 4; kk++) {
                int g = q * 4 + kk;
                (&v.x)[kk] = __fmul_rn(uni[g * 132 + c], sInv[g]);
            }
            *(float4*)(ob + (size_t)c * BEV_HW + q * 4) = v;
        }
    }
}

// ================= round-9 proven multi-kernel path (coop fallback) =========
__global__ __launch_bounds__(256) void k_count(const float* __restrict__ intr,
                                               const float* __restrict__ extr,
                                               const int* __restrict__ p_imgh,
                                               const int* __restrict__ p_imgw,
                                               const float* __restrict__ feat,
                                               int* __restrict__ cntArr,
                                               float* __restrict__ ft) {
    __shared__ float sKi[BNc * 9];
    __shared__ float sDb[Dc];
    __shared__ float buf[Cc * 17];
    int tid = threadIdx.x;
    setup_into(tid, intr, p_imgh, p_imgw, sKi, sDb);
    __syncthreads();
    int gid = blockIdx.x * 256 + tid;
    int cell = classify_point(gid, sKi, sDb, extr);
    if (cell >= 0) {
        int b = gid / (Nc * Dc * HWc);
        atomicAdd(&cntArr[b * BEV_HW + cell], 1);
    }
    if (blockIdx.x < BNc * (HWc / 16)) {
        int bn   = blockIdx.x / (HWc / 16);
        int tile = blockIdx.x % (HWc / 16);
        const float* fb = feat + (size_t)bn * Cc * HWc + tile * 16;
        for (int i = tid; i < Cc * 16; i += 256) {
            int c = i >> 4, hw = i & 15;
            buf[c * 17 + hw] = fb[c * HWc + hw];
        }
        __syncthreads();
        float* obt = ft + ((size_t)bn * HWc + tile * 16) * Cc;
        for (int i = tid; i < 16 * Cc; i += 256) {
            int r = i >> 7, ch = i & 127;
            obt[(size_t)r * Cc + ch] = buf[ch * 17 + r];
        }
    }
}

__global__ __launch_bounds__(512) void k_scan1(const int* __restrict__ cntArr,
                                               int* __restrict__ offs,
                                               int* __restrict__ fill,
                                               int* __restrict__ bsum) {
    __shared__ int s[512];
    int tid = threadIdx.x;
    int g = blockIdx.x * 512 + tid;
    int v = cntArr[g];
    s[tid] = v; __syncthreads();
    for (int st = 1; st < 512; st <<= 1) {
        int t = (tid >= st) ? s[tid - st] : 0;
        __syncthreads();
        s[tid] += t;
        __syncthreads();
    }
    int e = s[tid] - v;
    offs[g] = e;
    fill[g] = e;
    if (tid == 511) bsum[blockIdx.x] = s[511];
}

__global__ __launch_bounds__(256) void k_scan2(int* __restrict__ bsum, int* __restrict__ pEtot) {
    __shared__ int s[256];
    int tid = threadIdx.x;
    int v = bsum[tid];
    s[tid] = v; __syncthreads();
    for (int st = 1; st < 256; st <<= 1) {
        int t = (tid >= st) ? s[tid - st] : 0;
        __syncthreads();
        s[tid] += t;
        __syncthreads();
    }
    if (tid == 255) pEtot[0] = s[255];
    bsum[tid] = s[tid] - v;
}

__global__ __launch_bounds__(256) void k_fill(const float* __restrict__ intr,
                                              const float* __restrict__ extr,
                                              const int* __restrict__ p_imgh,
                                              const int* __restrict__ p_imgw,
                                              const float* __restrict__ depth,
                                              int* __restrict__ fill,
                                              const int* __restrict__ bsum,
                                              int2* __restrict__ e8) {
    __shared__ float sKi[BNc * 9];
    __shared__ float sDb[Dc];
    int tid = threadIdx.x;
    setup_into(tid, intr, p_imgh, p_imgw, sKi, sDb);
    __syncthreads();
    int gid = blockIdx.x * 256 + tid;
    int cell = classify_point(gid, sKi, sDb, extr);
    if (cell < 0) return;
    int p  = gid % HWc;
    int bn = gid / (Dc * HWc);
    int b  = bn / Nc;
    int seg = b * BEV_HW + cell;
    int pos = atomicAdd(&fill[seg], 1) + bsum[seg >> 9];
    int ray = (bn % Nc) * HWc + p;
    e8[pos] = make_int2(ray | (seg << 13), __float_as_int(depth[gid]));
}

__global__ __launch_bounds__(256) void k_gather2(const float2* __restrict__ ft2,
                                                 const int2* __restrict__ e8,
                                                 const int* __restrict__ cntArr,
                                                 const int* __restrict__ offs,
                                                 const int* __restrict__ bsum,
                                                 const int* __restrict__ pEtot,
                                                 float* __restrict__ acc) {
    const int WCH = 256;
    int wid  = blockIdx.x * 4 + (threadIdx.x >> 6);
    int lane = threadIdx.x & 63;
    int Etot = pEtot[0];
    int start = wid * WCH;
    if (start >= Etot) return;
    int end = start + WCH; if (end > Etot) end = Etot;
    int k0 = 0;
    if (start > 0) {
        int segP = e8[start - 1].x >> 13;
        k0 = offs[segP] + bsum[segP >> 9] + cntArr[segP];
        if (k0 >= end) return;
    }
    int segE = e8[end - 1].x >> 13;
    int kend = offs[segE] + bsum[segE >> 9] + cntArr[segE];
    int total = kend - k0;

    float2 a = make_float2(0.f, 0.f);
    int curc = -1;
    const int U = 8;
    int nb = total / U;
    if (nb > 0) {
        int2 e[U];
        #pragma unroll
        for (int u = 0; u < U; u++) e[u] = e8[k0 + u];
        for (int g = 0; g < nb; g++) {
            float2 f[U];
            #pragma unroll
            for (int u = 0; u < U; u++) {
                int sx = e[u].x;
                f[u] = ft2[((size_t)((sx >> 29) * NRAY) + (sx & 8191)) * 64 + lane];
            }
            int2 en[U];
            if (g + 1 < nb) {
                #pragma unroll
                for (int u = 0; u < U; u++) en[u] = e8[k0 + (g + 1) * U + u];
            } else {
                #pragma unroll
                for (int u = 0; u < U; u++) en[u] = e[u];
            }
            #pragma unroll
            for (int u = 0; u < U; u++) {
                int sg = e[u].x >> 13;
                if (sg != curc) {
                    if (curc >= 0) *(float2*)(acc + (size_t)curc * Cc + 2 * lane) = a;
                    curc = sg; a.x = 0.f; a.y = 0.f;
                }
                float ww = __int_as_float(e[u].y);
                a.x = fmaf(ww, f[u].x, a.x);
                a.y = fmaf(ww, f[u].y, a.y);
            }
            #pragma unroll
            for (int u = 0; u < U; u++) e[u] = en[u];
        }
    }
    for (int j = nb * U; j < total; j++) {
        int2 ee = e8[k0 + j];
        int sg = ee.x >> 13;
        if (sg != curc) {
            if (curc >= 0) *(float2*)(acc + (size_t)curc * Cc + 2 * lane) = a;
            curc = sg; a.x = 0.f; a.y = 0.f;
        }
        float ww = __int_as_float(ee.y);
        float2 f = ft2[((size_t)((ee.x >> 29) * NRAY) + (ee.x & 8191)) * 64 + lane];
        a.x = fmaf(ww, f.x, a.x);
        a.y = fmaf(ww, f.y, a.y);
    }
    if (curc >= 0) *(float2*)(acc + (size_t)curc * Cc + 2 * lane) = a;
}

__global__ __launch_bounds__(256) void k_finish(const float* __restrict__ acc,
                                                const int* __restrict__ cntArr,
                                                float* __restrict__ out) {
    __shared__ float res[GT * 132];
    __shared__ float sInv[GT];
    __shared__ int   sC[GT + 1];
    int seg0  = blockIdx.x * GT;
    int b     = seg0 >> 16;
    int cell0 = seg0 & 65535;
    int tid = threadIdx.x;
    if (tid < 64) {
        int n = (tid < GT) ? cntArr[seg0 + tid] : 0;
        int v = n;
        #pragma unroll
        for (int d = 1; d < GT; d <<= 1) {
            int y = __shfl_up(v, d, GT);
            if ((tid & (GT - 1)) >= d) v += y;
        }
        if (tid < GT) {
            sC[tid] = n;
            sInv[tid] = __fdiv_rn(1.0f, __fadd_rn((float)n, 1e-5f));
            if (tid == GT - 1) sC[GT] = v;
        }
    }
    __syncthreads();
    float* ob = out + (size_t)b * Cc * BEV_HW + cell0;
    if (sC[GT] == 0) {
        float4 z = {0.f, 0.f, 0.f, 0.f};
        for (int i = tid; i < Cc * GT / 4; i += 256) {
            int q = i & 3, c = i >> 2;
            *(float4*)(ob + (size_t)c * BEV_HW + q * 4) = z;
        }
        return;
    }
    {
        int g0 = tid >> 5, l32 = tid & 31;
        #pragma unroll
        for (int pass = 0; pass < 2; pass++) {
            int g = g0 + pass * 8;
            float4 v;
            if (sC[g] > 0) v = *(const float4*)(acc + (size_t)(seg0 + g) * Cc + 4 * l32);
            else           v = make_float4(0.f, 0.f, 0.f, 0.f);
            *(float4*)(&res[g * 132 + 4 * l32]) = v;
        }
    }
    __syncthreads();
    for (int i = tid; i < Cc * GT / 4; i += 256) {
        int q = i & 3, c = i >> 2;
        float4 v;
        #pragma unroll
        for (int kk = 0; kk < 4; kk++) {
            int g = q * 4 + kk;
            (&v.x)[kk] = __fmul_rn(res[g * 132 + c], sInv[g]);
        }
        *(float4*)(ob + (size_t)c * BEV_HW + q * 4) = v;
    }
}

// ======================= fallback (round-2 proven) ==========================
__global__ __launch_bounds__(256) void k_classifyF(const float* __restrict__ Ki_all,
                                                   const float* __restrict__ db,
                                                   const float* __restrict__ extr,
                                                   int* __restrict__ idxT,
                                                   float* __restrict__ cnt) {
    int gid = blockIdx.x * 256 + threadIdx.x;
    if (gid >= NPTS) return;
    int cell = classify_point(gid, Ki_all, db, extr);
    idxT[gid] = cell;
    if (cell >= 0) {
        int b = gid / (Nc * Dc * HWc);
        atomicAdd(&cnt[b * BEV_HW + cell], 1.0f);
    }
}

__global__ __launch_bounds__(256) void k_scatterF(const float* __restrict__ feat,
                                                  const float* __restrict__ depth,
                                                  const int* __restrict__ idxT,
                                                  float* __restrict__ out) {
    __shared__ float s_dw[HWc];
    __shared__ int   s_idx[HWc];
    int blk = blockIdx.x;
    int bn  = blk / Dc;
    int b   = bn / Nc;
    int tid = threadIdx.x;
    const float* dp = depth + (size_t)blk * HWc;
    const int*   ip = idxT  + (size_t)blk * HWc;
    for (int p = tid; p < HWc; p += 256) { s_dw[p] = dp[p]; s_idx[p] = ip[p]; }
    __syncthreads();
    const float* fb = feat + (size_t)bn * Cc * HWc;
    float*       ob = out  + (size_t)b  * Cc * BEV_HW;
    for (int c = 0; c < Cc; c++) {
        const float* f = fb + (size_t)c * HWc;
        float*       o = ob + (size_t)c * BEV_HW;
        for (int p = tid; p < HWc; p += 256) {
            int cell = s_idx[p];
            if (cell >= 0) atomicAdd(&o[cell], __fmul_rn(f[p], s_dw[p]));
        }
    }
}

__global__ __launch_bounds__(256) void k_normF(float* __restrict__ out,
                                               const float* __restrict__ cnt) {
    int i = blockIdx.x * 256 + threadIdx.x;
    const int total = Bc * Cc * BEV_HW / 4;
    if (i >= total) return;
    int q = i % (BEV_HW / 4);
    int b = i / (Cc * BEV_HW / 4);
    float4 v = ((float4*)out)[i];
    float4 cv = ((const float4*)cnt)[b * (BEV_HW / 4) + q];
    v.x = __fdiv_rn(v.x, __fadd_rn(cv.x, 1e-5f));
    v.y = __fdiv_rn(v.y, __fadd_rn(cv.y, 1e-5f));
    v.z = __fdiv_rn(v.z, __fadd_rn(cv.z, 1e-5f));
    v.w = __fdiv_rn(v.w, __fadd_rn(cv.w, 1e-5f));
    ((float4*)out)[i] = v;
}

// ===========================================================================
extern "C" void kernel_launch(void* const* d_in, const int* in_sizes, int n_in,
                              void* d_out, int out_size, void* d_ws, size_t ws_size,
                              hipStream_t stream) {
    const float* feat  = (const float*)d_in[0];
    const float* depth = (const float*)d_in[1];
    const float* intr  = (const float*)d_in[2];
    const float* extr  = (const float*)d_in[3];
    const int*   imh   = (const int*)d_in[4];
    const int*   imw   = (const int*)d_in[5];
    float* out = (float*)d_out;
    char*  ws  = (char*)d_ws;

    if (ws_size >= (size_t)WS_BIG) {
        int*   cntA  = (int*)(ws + OFF_CNT);
        int*   offs  = (int*)(ws + OFF_OFFS);
        int*   fill  = (int*)(ws + OFF_FILL);
        int*   bsum  = (int*)(ws + OFF_BSUM);
        int*   pEtot = (int*)(ws + OFF_ETOT);
        int2*  e8    = (int2*)(ws + OFF_E8);
        float* ft    = (float*)(ws + OFF_FT);
        float* acc   = (float*)(ws + OFF_ACC);

        // choose cooperative grid from the runtime's own occupancy calc
        int maxB = 0;
        hipError_t qe = hipOccupancyMaxActiveBlocksPerMultiprocessor(
            &maxB, (const void*)k_fused, 256, 0);
        int gridN = (qe == hipSuccess) ? maxB * 256 : 0;   // 256 CUs on MI355X
        if (gridN > 2048) gridN = 2048;

        bool coop_ok = false;
        if (gridN >= NSCANB) {
            void* args[] = {(void*)&intr, (void*)&extr, (void*)&imh, (void*)&imw,
                            (void*)&feat, (void*)&depth,
                            (void*)&cntA, (void*)&offs, (void*)&fill, (void*)&bsum,
                            (void*)&e8, (void*)&ft, (void*)&acc, (void*)&out};
            hipError_t err = hipLaunchCooperativeKernel((const void*)k_fused,
                                                        dim3(gridN), dim3(256),
                                                        args, 0, stream);
            if (err == hipSuccess) coop_ok = true;
            else (void)hipGetLastError();
        }
        if (!coop_ok) {
            hipMemsetAsync(cntA, 0, (size_t)NSEG * sizeof(int), stream);
            k_count<<<NPTS / 256, 256, 0, stream>>>(intr, extr, imh, imw, feat, cntA, ft);
            k_scan1<<<NSEG / 512, 512, 0, stream>>>(cntA, offs, fill, bsum);
            k_scan2<<<1, 256, 0, stream>>>(bsum, pEtot);
            k_fill<<<NPTS / 256, 256, 0, stream>>>(intr, extr, imh, imw, depth, fill, bsum, e8);
            k_gather2<<<NPTS / 1024, 256, 0, stream>>>((const float2*)ft, e8, cntA,
                                                       offs, bsum, pEtot, acc);
            k_finish<<<NTILE, 256, 0, stream>>>(acc, cntA, out);
        }
    } else {
        float* Ki   = (float*)(ws + OFF_KI);
        float* db   = (float*)(ws + OFF_DB);
        int*   idxT = (int*)(ws + OFF_FIDX);
        float* cnt  = (float*)(ws + OFF_FCNT);
        hipMemsetAsync(out, 0, (size_t)out_size * sizeof(float), stream);
        hipMemsetAsync(cnt, 0, (size_t)Bc * BEV_HW * sizeof(float), stream);
        k_setup<<<1, 64, 0, stream>>>(intr, extr, imh, imw, Ki, db);
        k_classifyF<<<(NPTS + 255) / 256, 256, 0, stream>>>(Ki, db, extr, idxT, cnt);
        k_scatterF<<<Bc * Nc * Dc, 256, 0, stream>>>(feat, depth, idxT, out);
        k_normF<<<(Bc * Cc * BEV_HW / 4 + 255) / 256, 256, 0, stream>>>(out, cnt);
    }
}

// Round 13
// 224.717 us; speedup vs baseline: 3.4692x; 3.4692x over previous
//
#include <hip/hip_runtime.h>
#include <hip/hip_bf16.h>

// Problem constants
#define Bc 2
#define Nc 6
#define Cc 128
#define Hc 16
#define Wc 44
#define Dc 64
#define HWc (Hc*Wc)          // 704
#define BNc (Bc*Nc)          // 12
#define NRAY (Nc*HWc)        // 4224
#define NPTS (Bc*Nc*Dc*HWc)  // 540672
#define BEV_W 256
#define BEV_H 256
#define BEV_HW (BEV_W*BEV_H) // 65536
#define NSEG (Bc*BEV_HW)     // 131072
#define GT 16
#define NTILE (NSEG/GT)      // 8192
#define GNB 1056             // gather2 blocks (4224 waves)
#define GNW (GNB*4)          // 4224 waves

// ---------------- workspace layout (bytes) ----------------
#define OFF_KI    0                      // fallback only
#define OFF_DB    512                    // fallback only
#define OFF_CNT   1024                   // int cnt[NSEG]      524288
#define OFF_OFFS  (OFF_CNT  + 524288)    // int offs[NSEG]     524288 (GLOBAL excl prefix)
#define OFF_FILL  (OFF_OFFS + 524288)    // int fill[NSEG]     524288 (starts = offs)
#define OFF_ETOT  (OFF_FILL + 524288)    // int Etot[1]
#define OFF_E8    (OFF_ETOT + 4096)      // int2 e8[NPTS]      4325376 {ray|seg<<13, w-bits}
#define OFF_FT    (OFF_E8   + 4325376)   // float ft[B][NRAY][128] 4325376
#define WS_NEED   (OFF_FT   + 4325376)   // ~9.8 MB
#define OFF_ACC   (OFF_FT   + 4325376)   // float acc[NSEG][128] 67108864
#define WS_BIG    (OFF_ACC  + 67108864)  // ~77 MB
#define OFF_FIDX  OFF_E8
#define OFF_FCNT  OFF_CNT

// ---------------------------------------------------------------------------
// numpy-f32-exact setup of Kinv (per bn) and dbins.
// ---------------------------------------------------------------------------
__device__ __forceinline__ void setup_into(int tid, const float* __restrict__ intr,
                                           const int* __restrict__ p_imgh,
                                           const int* __restrict__ p_imgw,
                                           float* Ki, float* db) {
    if (tid < Dc) {
        double v = 1.0 + (double)tid * (59.0 / 63.0);
        db[tid] = (tid == Dc - 1) ? 60.0f : (float)v;   // np.linspace endpoint = stop
    }
    if (tid >= BNc) return;
    double img_h = (double)p_imgh[0];
    double img_w = (double)p_imgw[0];
    double scale_x = (double)Wc / (img_w / 16.0);
    double scale_y = (double)Hc / (img_h / 16.0);
    float rs0 = (float)(16.0 / scale_x);
    float rs1 = (float)(16.0 / scale_y);
    float rs2 = 1.0f;
    const float* K = intr + tid * 9;
    float k0 = __fmul_rn(K[0], rs0), k1 = __fmul_rn(K[1], rs0), k2 = __fmul_rn(K[2], rs0);
    float k3 = __fmul_rn(K[3], rs1), k4 = __fmul_rn(K[4], rs1), k5 = __fmul_rn(K[5], rs1);
    float k6 = __fmul_rn(K[6], rs2), k7 = __fmul_rn(K[7], rs2), k8 = __fmul_rn(K[8], rs2);
    float c0 = __fsub_rn(__fmul_rn(k4,k8), __fmul_rn(k5,k7));
    float c1 = __fsub_rn(__fmul_rn(k3,k8), __fmul_rn(k5,k6));
    float c2 = __fsub_rn(__fmul_rn(k3,k7), __fmul_rn(k4,k6));
    float det = __fadd_rn(__fsub_rn(__fmul_rn(k0,c0), __fmul_rn(k1,c1)), __fmul_rn(k2,c2));
    float* o = Ki + tid * 9;
    o[0] = __fdiv_rn(c0, det);
    o[1] = __fdiv_rn(__fsub_rn(__fmul_rn(k2,k7), __fmul_rn(k1,k8)), det);
    o[2] = __fdiv_rn(__fsub_rn(__fmul_rn(k1,k5), __fmul_rn(k2,k4)), det);
    o[3] = __fdiv_rn(__fsub_rn(__fmul_rn(k5,k6), __fmul_rn(k3,k8)), det);
    o[4] = __fdiv_rn(__fsub_rn(__fmul_rn(k0,k8), __fmul_rn(k2,k6)), det);
    o[5] = __fdiv_rn(__fsub_rn(__fmul_rn(k2,k3), __fmul_rn(k0,k5)), det);
    o[6] = __fdiv_rn(c2, det);
    o[7] = __fdiv_rn(__fsub_rn(__fmul_rn(k1,k6), __fmul_rn(k0,k7)), det);
    o[8] = __fdiv_rn(__fsub_rn(__fmul_rn(k0,k4), __fmul_rn(k1,k3)), det);
}

__global__ void k_setup(const float* __restrict__ intr, const float* __restrict__ extr,
                        const int* __restrict__ p_imgh, const int* __restrict__ p_imgw,
                        float* __restrict__ Ki, float* __restrict__ db) {
    setup_into(threadIdx.x, intr, p_imgh, p_imgw, Ki, db);
}

// ---------------------------------------------------------------------------
// numpy-f32-exact classify: point gid -> BEV cell (or -1)
// ---------------------------------------------------------------------------
__device__ __forceinline__ int classify_point(int gid, const float* Ki_all,
                                              const float* db, const float* extr) {
    int p   = gid % HWc;
    int tmp = gid / HWc;
    int d   = tmp % Dc;
    int bn  = tmp / Dc;
    int w = p % Wc, h = p / Wc;
    float dd = db[d];
    float ud = __fmul_rn((float)w, dd);
    float vd = __fmul_rn((float)h, dd);
    const float* Ki = Ki_all + bn * 9;
    float pcx = fmaf(Ki[2], dd, fmaf(Ki[1], vd, __fmul_rn(Ki[0], ud)));
    float pcy = fmaf(Ki[5], dd, fmaf(Ki[4], vd, __fmul_rn(Ki[3], ud)));
    float pcz = fmaf(Ki[8], dd, fmaf(Ki[7], vd, __fmul_rn(Ki[6], ud)));
    const float* E = extr + bn * 16;
    float px = __fadd_rn(fmaf(E[2],  pcz, fmaf(E[1], pcy, __fmul_rn(E[0], pcx))), E[3]);
    float py = __fadd_rn(fmaf(E[6],  pcz, fmaf(E[5], pcy, __fmul_rn(E[4], pcx))), E[7]);
    float pz = __fadd_rn(fmaf(E[10], pcz, fmaf(E[9], pcy, __fmul_rn(E[8], pcx))), E[11]);
    float fx = __fdiv_rn(__fsub_rn(px, -51.2f), 0.4f);
    float fy = __fdiv_rn(__fsub_rn(py, -51.2f), 0.4f);
    int xi = (int)fx;
    int yi = (int)fy;
    bool valid = (xi >= 0) && (xi < BEV_W) && (yi >= 0) && (yi < BEV_H)
              && (pz >= -5.0f) && (pz <= 3.0f);
    return valid ? (yi * BEV_W + xi) : -1;
}

// ---------------------------------------------------------------------------
// Kernel A: count (+ fused setup in LDS, + fused transpose in first 528 blocks)
// ---------------------------------------------------------------------------
__global__ __launch_bounds__(256) void k_count(const float* __restrict__ intr,
                                               const float* __restrict__ extr,
                                               const int* __restrict__ p_imgh,
                                               const int* __restrict__ p_imgw,
                                               const float* __restrict__ feat,
                                               int* __restrict__ cntArr,
                                               float* __restrict__ ft) {
    __shared__ float sKi[BNc * 9];
    __shared__ float sDb[Dc];
    __shared__ float buf[Cc * 17];
    int tid = threadIdx.x;
    setup_into(tid, intr, p_imgh, p_imgw, sKi, sDb);
    __syncthreads();
    int gid = blockIdx.x * 256 + tid;      // grid = NPTS/256 exactly
    int cell = classify_point(gid, sKi, sDb, extr);
    if (cell >= 0) {
        int b = gid / (Nc * Dc * HWc);
        atomicAdd(&cntArr[b * BEV_HW + cell], 1);
    }
    if (blockIdx.x < BNc * (HWc / 16)) {
        int bn   = blockIdx.x / (HWc / 16);
        int tile = blockIdx.x % (HWc / 16);
        const float* fb = feat + (size_t)bn * Cc * HWc + tile * 16;
        for (int i = tid; i < Cc * 16; i += 256) {
            int c = i >> 4, hw = i & 15;
            buf[c * 17 + hw] = fb[c * HWc + hw];
        }
        __syncthreads();
        float* obt = ft + ((size_t)bn * HWc + tile * 16) * Cc;
        for (int i = tid; i < 16 * Cc; i += 256) {
            int r = i >> 7, ch = i & 127;
            obt[(size_t)r * Cc + ch] = buf[ch * 17 + r];
        }
    }
}

// ---------------------------------------------------------------------------
// Kernel B: single-dispatch full scan. One block, 1024 threads; each thread
// owns 128 consecutive counts (NSEG = 1024*128 exactly). Pass 1: per-thread
// sum; LDS scan of the 1024 partials; pass 2: write GLOBAL exclusive
// prefixes to offs and fill. Also writes Etot. Replaces scan1+scan2 (one
// dispatch saved; removes bsum indirection from all consumers).
// ---------------------------------------------------------------------------
__global__ __launch_bounds__(1024) void k_scanAll(const int* __restrict__ cnt,
                                                  int* __restrict__ offs,
                                                  int* __restrict__ fill,
                                                  int* __restrict__ pEtot) {
    __shared__ int part[1024];
    int tid = threadIdx.x;
    const int4* c4 = (const int4*)(cnt + tid * 128);
    int s = 0;
    #pragma unroll 4
    for (int i = 0; i < 32; i++) {
        int4 v = c4[i];
        s += v.x + v.y + v.z + v.w;
    }
    part[tid] = s;
    __syncthreads();
    for (int st = 1; st < 1024; st <<= 1) {
        int t = (tid >= st) ? part[tid - st] : 0;
        __syncthreads();
        part[tid] += t;
        __syncthreads();
    }
    int run = part[tid] - s;                 // global exclusive base for this thread
    if (tid == 1023) pEtot[0] = part[1023];
    int4* o4 = (int4*)(offs + tid * 128);
    int4* f4 = (int4*)(fill + tid * 128);
    #pragma unroll 4
    for (int i = 0; i < 32; i++) {
        int4 v = c4[i];
        int4 o;
        o.x = run; run += v.x;
        o.y = run; run += v.y;
        o.z = run; run += v.z;
        o.w = run; run += v.w;
        o4[i] = o;
        f4[i] = o;
    }
}

// ---------------------------------------------------------------------------
// Kernel C: fill packed entries {ray | seg<<13, weight-bits}. fill[] holds
// GLOBAL offsets now (no bsum add).
// ---------------------------------------------------------------------------
__global__ __launch_bounds__(256) void k_fill(const float* __restrict__ intr,
                                              const float* __restrict__ extr,
                                              const int* __restrict__ p_imgh,
                                              const int* __restrict__ p_imgw,
                                              const float* __restrict__ depth,
                                              int* __restrict__ fill,
                                              int2* __restrict__ e8) {
    __shared__ float sKi[BNc * 9];
    __shared__ float sDb[Dc];
    int tid = threadIdx.x;
    setup_into(tid, intr, p_imgh, p_imgw, sKi, sDb);
    __syncthreads();
    int gid = blockIdx.x * 256 + tid;
    int cell = classify_point(gid, sKi, sDb, extr);
    if (cell < 0) return;
    int p  = gid % HWc;
    int bn = gid / (Dc * HWc);
    int b  = bn / Nc;
    int seg = b * BEV_HW + cell;
    int pos = atomicAdd(&fill[seg], 1);
    int ray = (bn % Nc) * HWc + p;
    e8[pos] = make_int2(ray | (seg << 13), __float_as_int(depth[gid]));
}

// ---------------------------------------------------------------------------
// Kernel D: entry-parallel ownership gather -> acc[seg][128].
// 4224 waves (1056 blocks); per-wave chunk WCH computed from Etot in-kernel
// (round 9 used fixed 256 -> only 528 blocks ~2/CU, latency-bound; this
// doubles resident waves and halves chunk length). offs[] is global now.
// ---------------------------------------------------------------------------
__global__ __launch_bounds__(256) void k_gather2(const float2* __restrict__ ft2,
                                                 const int2* __restrict__ e8,
                                                 const int* __restrict__ cntArr,
                                                 const int* __restrict__ offs,
                                                 const int* __restrict__ pEtot,
                                                 float* __restrict__ acc) {
    int wid  = blockIdx.x * 4 + (threadIdx.x >> 6);
    int lane = threadIdx.x & 63;
    int Etot = pEtot[0];
    int WCH  = (Etot + GNW - 1) / GNW;
    if (WCH <= 0) return;
    int start = wid * WCH;
    if (start >= Etot) return;
    int end = start + WCH; if (end > Etot) end = Etot;
    int k0 = 0;
    if (start > 0) {
        int segP = e8[start - 1].x >> 13;
        k0 = offs[segP] + cntArr[segP];          // end of segP's run
        if (k0 >= end) return;                   // no cell starts in range
    }
    int segE = e8[end - 1].x >> 13;
    int kend = offs[segE] + cntArr[segE];        // extend through straddler
    int total = kend - k0;

    float2 a = make_float2(0.f, 0.f);
    int curc = -1;
    const int U = 8;
    int nb = total / U;
    if (nb > 0) {
        int2 e[U];
        #pragma unroll
        for (int u = 0; u < U; u++) e[u] = e8[k0 + u];
        for (int g = 0; g < nb; g++) {
            float2 f[U];
            #pragma unroll
            for (int u = 0; u < U; u++) {
                int sx = e[u].x;
                f[u] = ft2[((size_t)((sx >> 29) * NRAY) + (sx & 8191)) * 64 + lane];
            }
            int2 en[U];
            if (g + 1 < nb) {
                #pragma unroll
                for (int u = 0; u < U; u++) en[u] = e8[k0 + (g + 1) * U + u];
            } else {
                #pragma unroll
                for (int u = 0; u < U; u++) en[u] = e[u];
            }
            #pragma unroll
            for (int u = 0; u < U; u++) {
                int sg = e[u].x >> 13;
                if (sg != curc) {
                    if (curc >= 0) *(float2*)(acc + (size_t)curc * Cc + 2 * lane) = a;
                    curc = sg; a.x = 0.f; a.y = 0.f;
                }
                float ww = __int_as_float(e[u].y);
                a.x = fmaf(ww, f[u].x, a.x);
                a.y = fmaf(ww, f[u].y, a.y);
            }
            #pragma unroll
            for (int u = 0; u < U; u++) e[u] = en[u];
        }
    }
    for (int j = nb * U; j < total; j++) {
        int2 ee = e8[k0 + j];
        int sg = ee.x >> 13;
        if (sg != curc) {
            if (curc >= 0) *(float2*)(acc + (size_t)curc * Cc + 2 * lane) = a;
            curc = sg; a.x = 0.f; a.y = 0.f;
        }
        float ww = __int_as_float(ee.y);
        float2 f = ft2[((size_t)((ee.x >> 29) * NRAY) + (ee.x & 8191)) * 64 + lane];
        a.x = fmaf(ww, f.x, a.x);
        a.y = fmaf(ww, f.y, a.y);
    }
    if (curc >= 0) *(float2*)(acc + (size_t)curc * Cc + 2 * lane) = a;
}

// ---------------------------------------------------------------------------
// Kernel E: finish — normalize + transpose acc[seg][c] -> out[b][c][cell].
// ---------------------------------------------------------------------------
__global__ __launch_bounds__(256) void k_finish(const float* __restrict__ acc,
                                                const int* __restrict__ cntArr,
                                                float* __restrict__ out) {
    __shared__ float res[GT * 132];
    __shared__ float sInv[GT];
    __shared__ int   sC[GT + 1];
    int seg0  = blockIdx.x * GT;
    int b     = seg0 >> 16;
    int cell0 = seg0 & 65535;
    int tid = threadIdx.x;
    if (tid < 64) {
        int n = (tid < GT) ? cntArr[seg0 + tid] : 0;
        int v = n;
        #pragma unroll
        for (int d = 1; d < GT; d <<= 1) {
            int y = __shfl_up(v, d, GT);
            if ((tid & (GT - 1)) >= d) v += y;
        }
        if (tid < GT) {
            sC[tid] = n;
            sInv[tid] = __fdiv_rn(1.0f, __fadd_rn((float)n, 1e-5f));
            if (tid == GT - 1) sC[GT] = v;
        }
    }
    __syncthreads();
    float* ob = out + (size_t)b * Cc * BEV_HW + cell0;
    if (sC[GT] == 0) {                       // all 16 cells empty
        float4 z = {0.f, 0.f, 0.f, 0.f};
        for (int i = tid; i < Cc * GT / 4; i += 256) {
            int q = i & 3, c = i >> 2;
            *(float4*)(ob + (size_t)c * BEV_HW + q * 4) = z;
        }
        return;
    }
    {
        int g0 = tid >> 5, l32 = tid & 31;
        #pragma unroll
        for (int pass = 0; pass < 2; pass++) {
            int g = g0 + pass * 8;
            float4 v;
            if (sC[g] > 0) v = *(const float4*)(acc + (size_t)(seg0 + g) * Cc + 4 * l32);
            else           v = make_float4(0.f, 0.f, 0.f, 0.f);
            *(float4*)(&res[g * 132 + 4 * l32]) = v;
        }
    }
    __syncthreads();
    for (int i = tid; i < Cc * GT / 4; i += 256) {
        int q = i & 3, c = i >> 2;
        float4 v;
        #pragma unroll
        for (int kk = 0; kk < 4; kk++) {
            int g = q * 4 + kk;
            (&v.x)[kk] = __fmul_rn(res[g * 132 + c], sInv[g]);
        }
        *(float4*)(ob + (size_t)c * BEV_HW + q * 4) = v;
    }
}

// ======================= fallback (round-2 proven) ==========================
__global__ __launch_bounds__(256) void k_classifyF(const float* __restrict__ Ki_all,
                                                   const float* __restrict__ db,
                                                   const float* __restrict__ extr,
                                                   int* __restrict__ idxT,
                                                   float* __restrict__ cnt) {
    int gid = blockIdx.x * 256 + threadIdx.x;
    if (gid >= NPTS) return;
    int cell = classify_point(gid, Ki_all, db, extr);
    idxT[gid] = cell;
    if (cell >= 0) {
        int b = gid / (Nc * Dc * HWc);
        atomicAdd(&cnt[b * BEV_HW + cell], 1.0f);
    }
}

__global__ __launch_bounds__(256) void k_scatterF(const float* __restrict__ feat,
                                                  const float* __restrict__ depth,
                                                  const int* __restrict__ idxT,
                                                  float* __restrict__ out) {
    __shared__ float s_dw[HWc];
    __shared__ int   s_idx[HWc];
    int blk = blockIdx.x;
    int bn  = blk / Dc;
    int b   = bn / Nc;
    int tid = threadIdx.x;
    const float* dp = depth + (size_t)blk * HWc;
    const int*   ip = idxT  + (size_t)blk * HWc;
    for (int p = tid; p < HWc; p += 256) { s_dw[p] = dp[p]; s_idx[p] = ip[p]; }
    __syncthreads();
    const float* fb = feat + (size_t)bn * Cc * HWc;
    float*       ob = out  + (size_t)b  * Cc * BEV_HW;
    for (int c = 0; c < Cc; c++) {
        const float* f = fb + (size_t)c * HWc;
        float*       o = ob + (size_t)c * BEV_HW;
        for (int p = tid; p < HWc; p += 256) {
            int cell = s_idx[p];
            if (cell >= 0) atomicAdd(&o[cell], __fmul_rn(f[p], s_dw[p]));
        }
    }
}

__global__ __launch_bounds__(256) void k_normF(float* __restrict__ out,
                                               const float* __restrict__ cnt) {
    int i = blockIdx.x * 256 + threadIdx.x;
    const int total = Bc * Cc * BEV_HW / 4;
    if (i >= total) return;
    int q = i % (BEV_HW / 4);
    int b = i / (Cc * BEV_HW / 4);
    float4 v = ((float4*)out)[i];
    float4 cv = ((const float4*)cnt)[b * (BEV_HW / 4) + q];
    v.x = __fdiv_rn(v.x, __fadd_rn(cv.x, 1e-5f));
    v.y = __fdiv_rn(v.y, __fadd_rn(cv.y, 1e-5f));
    v.z = __fdiv_rn(v.z, __fadd_rn(cv.z, 1e-5f));
    v.w = __fdiv_rn(v.w, __fadd_rn(cv.w, 1e-5f));
    ((float4*)out)[i] = v;
}

// ===========================================================================
extern "C" void kernel_launch(void* const* d_in, const int* in_sizes, int n_in,
                              void* d_out, int out_size, void* d_ws, size_t ws_size,
                              hipStream_t stream) {
    const float* feat  = (const float*)d_in[0];
    const float* depth = (const float*)d_in[1];
    const float* intr  = (const float*)d_in[2];
    const float* extr  = (const float*)d_in[3];
    const int*   imh   = (const int*)d_in[4];
    const int*   imw   = (const int*)d_in[5];
    float* out = (float*)d_out;
    char*  ws  = (char*)d_ws;

    if (ws_size >= (size_t)WS_BIG) {
        int*   cntA  = (int*)(ws + OFF_CNT);
        int*   offs  = (int*)(ws + OFF_OFFS);
        int*   fill  = (int*)(ws + OFF_FILL);
        int*   pEtot = (int*)(ws + OFF_ETOT);
        int2*  e8    = (int2*)(ws + OFF_E8);
        float* ft    = (float*)(ws + OFF_FT);
        float* acc   = (float*)(ws + OFF_ACC);

        hipMemsetAsync(cntA, 0, (size_t)NSEG * sizeof(int), stream);
        k_count<<<NPTS / 256, 256, 0, stream>>>(intr, extr, imh, imw, feat, cntA, ft);
        k_scanAll<<<1, 1024, 0, stream>>>(cntA, offs, fill, pEtot);
        k_fill<<<NPTS / 256, 256, 0, stream>>>(intr, extr, imh, imw, depth, fill, e8);
        k_gather2<<<GNB, 256, 0, stream>>>((const float2*)ft, e8, cntA, offs, pEtot, acc);
        k_finish<<<NTILE, 256, 0, stream>>>(acc, cntA, out);
    } else {
        float* Ki   = (float*)(ws + OFF_KI);
        float* db   = (float*)(ws + OFF_DB);
        int*   idxT = (int*)(ws + OFF_FIDX);
        float* cnt  = (float*)(ws + OFF_FCNT);
        hipMemsetAsync(out, 0, (size_t)out_size * sizeof(float), stream);
        hipMemsetAsync(cnt, 0, (size_t)Bc * BEV_HW * sizeof(float), stream);
        k_setup<<<1, 64, 0, stream>>>(intr, extr, imh, imw, Ki, db);
        k_classifyF<<<(NPTS + 255) / 256, 256, 0, stream>>>(Ki, db, extr, idxT, cnt);
        k_scatterF<<<Bc * Nc * Dc, 256, 0, stream>>>(feat, depth, idxT, out);
        k_normF<<<(Bc * Cc * BEV_HW / 4 + 255) / 256, 256, 0, stream>>>(out, cnt);
    }
}

// Round 15
// 165.113 us; speedup vs baseline: 4.7215x; 1.3610x over previous
//
#include <hip/hip_runtime.h>
#include <hip/hip_bf16.h>

// Problem constants
#define Bc 2
#define Nc 6
#define Cc 128
#define Hc 16
#define Wc 44
#define Dc 64
#define HWc (Hc*Wc)          // 704
#define BNc (Bc*Nc)          // 12
#define NRAY (Nc*HWc)        // 4224
#define NPTS (Bc*Nc*Dc*HWc)  // 540672
#define BEV_W 256
#define BEV_H 256
#define BEV_HW (BEV_W*BEV_H) // 65536
#define NSEG (Bc*BEV_HW)     // 131072
#define GT 16
#define NTILE (NSEG/GT)      // 8192
#define NSCANB 512           // scan blocks (256 segs each)
#define GNB 1056             // gather2 blocks
#define GNW (GNB*4)          // 4224 waves

// ---------------- workspace layout (bytes) ----------------
#define OFF_KI    0                      // fallback only
#define OFF_DB    512                    // fallback only
#define OFF_CNT   1024                   // int cnt[NSEG]      524288
#define OFF_OFFS  (OFF_CNT  + 524288)    // int offs[NSEG]     524288 (block-local excl)
#define OFF_FILL  (OFF_OFFS + 524288)    // int fill[NSEG]     524288
#define OFF_BSUM  (OFF_FILL + 524288)    // int bsum[512]      2048 (raw block sums)
#define OFF_E8    (OFF_BSUM + 4096)      // int2 e8[NPTS]      4325376 {ray|seg<<13, w}
#define OFF_FT    (OFF_E8   + 4325376)   // float ft[B][NRAY][128] 4325376
#define WS_NEED   (OFF_FT   + 4325376)   // ~9.8 MB
#define OFF_ACC   (OFF_FT   + 4325376)   // float acc[NSEG][128] 67108864
#define WS_BIG    (OFF_ACC  + 67108864)  // ~77 MB
#define OFF_FIDX  OFF_E8
#define OFF_FCNT  OFF_CNT

// ---------------------------------------------------------------------------
// numpy-f32-exact setup of Kinv (per bn) and dbins.
// ---------------------------------------------------------------------------
__device__ __forceinline__ void setup_into(int tid, const float* __restrict__ intr,
                                           const int* __restrict__ p_imgh,
                                           const int* __restrict__ p_imgw,
                                           float* Ki, float* db) {
    if (tid < Dc) {
        double v = 1.0 + (double)tid * (59.0 / 63.0);
        db[tid] = (tid == Dc - 1) ? 60.0f : (float)v;   // np.linspace endpoint = stop
    }
    if (tid >= BNc) return;
    double img_h = (double)p_imgh[0];
    double img_w = (double)p_imgw[0];
    double scale_x = (double)Wc / (img_w / 16.0);
    double scale_y = (double)Hc / (img_h / 16.0);
    float rs0 = (float)(16.0 / scale_x);
    float rs1 = (float)(16.0 / scale_y);
    float rs2 = 1.0f;
    const float* K = intr + tid * 9;
    float k0 = __fmul_rn(K[0], rs0), k1 = __fmul_rn(K[1], rs0), k2 = __fmul_rn(K[2], rs0);
    float k3 = __fmul_rn(K[3], rs1), k4 = __fmul_rn(K[4], rs1), k5 = __fmul_rn(K[5], rs1);
    float k6 = __fmul_rn(K[6], rs2), k7 = __fmul_rn(K[7], rs2), k8 = __fmul_rn(K[8], rs2);
    float c0 = __fsub_rn(__fmul_rn(k4,k8), __fmul_rn(k5,k7));
    float c1 = __fsub_rn(__fmul_rn(k3,k8), __fmul_rn(k5,k6));
    float c2 = __fsub_rn(__fmul_rn(k3,k7), __fmul_rn(k4,k6));
    float det = __fadd_rn(__fsub_rn(__fmul_rn(k0,c0), __fmul_rn(k1,c1)), __fmul_rn(k2,c2));
    float* o = Ki + tid * 9;
    o[0] = __fdiv_rn(c0, det);
    o[1] = __fdiv_rn(__fsub_rn(__fmul_rn(k2,k7), __fmul_rn(k1,k8)), det);
    o[2] = __fdiv_rn(__fsub_rn(__fmul_rn(k1,k5), __fmul_rn(k2,k4)), det);
    o[3] = __fdiv_rn(__fsub_rn(__fmul_rn(k5,k6), __fmul_rn(k3,k8)), det);
    o[4] = __fdiv_rn(__fsub_rn(__fmul_rn(k0,k8), __fmul_rn(k2,k6)), det);
    o[5] = __fdiv_rn(__fsub_rn(__fmul_rn(k2,k3), __fmul_rn(k0,k5)), det);
    o[6] = __fdiv_rn(c2, det);
    o[7] = __fdiv_rn(__fsub_rn(__fmul_rn(k1,k6), __fmul_rn(k0,k7)), det);
    o[8] = __fdiv_rn(__fsub_rn(__fmul_rn(k0,k4), __fmul_rn(k1,k3)), det);
}

__global__ void k_setup(const float* __restrict__ intr, const float* __restrict__ extr,
                        const int* __restrict__ p_imgh, const int* __restrict__ p_imgw,
                        float* __restrict__ Ki, float* __restrict__ db) {
    setup_into(threadIdx.x, intr, p_imgh, p_imgw, Ki, db);
}

// ---------------------------------------------------------------------------
// numpy-f32-exact classify: point gid -> BEV cell (or -1)
// ---------------------------------------------------------------------------
__device__ __forceinline__ int classify_point(int gid, const float* Ki_all,
                                              const float* db, const float* extr) {
    int p   = gid % HWc;
    int tmp = gid / HWc;
    int d   = tmp % Dc;
    int bn  = tmp / Dc;
    int w = p % Wc, h = p / Wc;
    float dd = db[d];
    float ud = __fmul_rn((float)w, dd);
    float vd = __fmul_rn((float)h, dd);
    const float* Ki = Ki_all + bn * 9;
    float pcx = fmaf(Ki[2], dd, fmaf(Ki[1], vd, __fmul_rn(Ki[0], ud)));
    float pcy = fmaf(Ki[5], dd, fmaf(Ki[4], vd, __fmul_rn(Ki[3], ud)));
    float pcz = fmaf(Ki[8], dd, fmaf(Ki[7], vd, __fmul_rn(Ki[6], ud)));
    const float* E = extr + bn * 16;
    float px = __fadd_rn(fmaf(E[2],  pcz, fmaf(E[1], pcy, __fmul_rn(E[0], pcx))), E[3]);
    float py = __fadd_rn(fmaf(E[6],  pcz, fmaf(E[5], pcy, __fmul_rn(E[4], pcx))), E[7]);
    float pz = __fadd_rn(fmaf(E[10], pcz, fmaf(E[9], pcy, __fmul_rn(E[8], pcx))), E[11]);
    float fx = __fdiv_rn(__fsub_rn(px, -51.2f), 0.4f);
    float fy = __fdiv_rn(__fsub_rn(py, -51.2f), 0.4f);
    int xi = (int)fx;
    int yi = (int)fy;
    bool valid = (xi >= 0) && (xi < BEV_W) && (yi >= 0) && (yi < BEV_H)
              && (pz >= -5.0f) && (pz <= 3.0f);
    return valid ? (yi * BEV_W + xi) : -1;
}

// ---------------------------------------------------------------------------
// bsum preamble (proven in coop rounds 11/12 phase 2B): scan bsum[512] into
// LDS sB (exclusive bases); also produces Etot.
// ---------------------------------------------------------------------------
__device__ __forceinline__ void scan_bsum(int tid, const int* __restrict__ bsum,
                                          int* sB, int* su, int* pEtotS) {
    int2 v2 = ((const int2*)bsum)[tid];      // 512 ints = 256 int2
    int s = v2.x + v2.y;
    su[tid] = s;
    __syncthreads();
    for (int st = 1; st < 256; st <<= 1) {
        int t2 = (tid >= st) ? su[tid - st] : 0;
        __syncthreads();
        su[tid] += t2;
        __syncthreads();
    }
    int base = su[tid] - s;                  // exclusive
    sB[2 * tid]     = base;
    sB[2 * tid + 1] = base + v2.x;
    if (tid == 255) *pEtotS = base + s;
    __syncthreads();
}

// ---------------------------------------------------------------------------
// Kernel A: count (+ fused setup in LDS, + fused transpose in first 528 blocks)
// ---------------------------------------------------------------------------
__global__ __launch_bounds__(256) void k_count(const float* __restrict__ intr,
                                               const float* __restrict__ extr,
                                               const int* __restrict__ p_imgh,
                                               const int* __restrict__ p_imgw,
                                               const float* __restrict__ feat,
                                               int* __restrict__ cntArr,
                                               float* __restrict__ ft) {
    __shared__ float sKi[BNc * 9];
    __shared__ float sDb[Dc];
    __shared__ float buf[Cc * 17];
    int tid = threadIdx.x;
    setup_into(tid, intr, p_imgh, p_imgw, sKi, sDb);
    __syncthreads();
    int gid = blockIdx.x * 256 + tid;      // grid = NPTS/256 exactly
    int cell = classify_point(gid, sKi, sDb, extr);
    if (cell >= 0) {
        int b = gid / (Nc * Dc * HWc);
        atomicAdd(&cntArr[b * BEV_HW + cell], 1);
    }
    if (blockIdx.x < BNc * (HWc / 16)) {
        int bn   = blockIdx.x / (HWc / 16);
        int tile = blockIdx.x % (HWc / 16);
        const float* fb = feat + (size_t)bn * Cc * HWc + tile * 16;
        for (int i = tid; i < Cc * 16; i += 256) {
            int c = i >> 4, hw = i & 15;
            buf[c * 17 + hw] = fb[c * HWc + hw];
        }
        __syncthreads();
        float* obt = ft + ((size_t)bn * HWc + tile * 16) * Cc;
        for (int i = tid; i < 16 * Cc; i += 256) {
            int r = i >> 7, ch = i & 127;
            obt[(size_t)r * Cc + ch] = buf[ch * 17 + r];
        }
    }
}

// ---------------------------------------------------------------------------
// Kernel B: parallel scan — 512 blocks x 256 threads, each block scans its
// 256 counts (block-local exclusive) + writes its raw sum to bsum[bid].
// (Round-13's single-block k_scanAll was single-CU memory-bound: 68 us.)
// ---------------------------------------------------------------------------
__global__ __launch_bounds__(256) void k_scanB(const int* __restrict__ cntArr,
                                               int* __restrict__ offs,
                                               int* __restrict__ fill,
                                               int* __restrict__ bsum) {
    __shared__ int su[256];
    int tid = threadIdx.x;
    int g = blockIdx.x * 256 + tid;
    int v = cntArr[g];
    su[tid] = v;
    __syncthreads();
    for (int st = 1; st < 256; st <<= 1) {
        int t2 = (tid >= st) ? su[tid - st] : 0;
        __syncthreads();
        su[tid] += t2;
        __syncthreads();
    }
    int e = su[tid] - v;
    offs[g] = e;
    fill[g] = e;
    if (tid == 255) bsum[blockIdx.x] = su[255];
}

// ---------------------------------------------------------------------------
// Kernel C: fill packed entries {ray | seg<<13, weight-bits}. Starts with
// the bsum preamble (LDS scan of 512 block sums) -> global positions.
// ---------------------------------------------------------------------------
__global__ __launch_bounds__(256) void k_fill(const float* __restrict__ intr,
                                              const float* __restrict__ extr,
                                              const int* __restrict__ p_imgh,
                                              const int* __restrict__ p_imgw,
                                              const float* __restrict__ depth,
                                              int* __restrict__ fill,
                                              const int* __restrict__ bsum,
                                              int2* __restrict__ e8) {
    __shared__ float sKi[BNc * 9];
    __shared__ float sDb[Dc];
    __shared__ int   sB[NSCANB];
    __shared__ int   su[256];
    __shared__ int   sEtot;
    int tid = threadIdx.x;
    setup_into(tid, intr, p_imgh, p_imgw, sKi, sDb);
    scan_bsum(tid, bsum, sB, su, &sEtot);
    int gid = blockIdx.x * 256 + tid;
    int cell = classify_point(gid, sKi, sDb, extr);
    if (cell < 0) return;
    int p  = gid % HWc;
    int bn = gid / (Dc * HWc);
    int b  = bn / Nc;
    int seg = b * BEV_HW + cell;
    int pos = atomicAdd(&fill[seg], 1) + sB[seg >> 8];
    int ray = (bn % Nc) * HWc + p;
    e8[pos] = make_int2(ray | (seg << 13), __float_as_int(depth[gid]));
}

// ---------------------------------------------------------------------------
// Kernel D: entry-parallel ownership gather -> acc[seg][128]. 4224 waves;
// per-wave chunk from Etot (computed in preamble). Contiguous walk,
// flush-on-cell-change = coalesced 512 B pure store. No atomics, no init.
// ---------------------------------------------------------------------------
__global__ __launch_bounds__(256) void k_gather2(const float2* __restrict__ ft2,
                                                 const int2* __restrict__ e8,
                                                 const int* __restrict__ cntArr,
                                                 const int* __restrict__ offs,
                                                 const int* __restrict__ bsum,
                                                 float* __restrict__ acc) {
    __shared__ int sB[NSCANB];
    __shared__ int su[256];
    __shared__ int sEtot;
    int tid = threadIdx.x;
    scan_bsum(tid, bsum, sB, su, &sEtot);
    int Etot = sEtot;
    int wid  = blockIdx.x * 4 + (tid >> 6);
    int lane = tid & 63;
    int WCH  = (Etot + GNW - 1) / GNW;
    if (WCH <= 0) return;
    int start = wid * WCH;
    if (start >= Etot) return;
    int end = start + WCH; if (end > Etot) end = Etot;
    int k0 = 0;
    if (start > 0) {
        int segP = e8[start - 1].x >> 13;
        k0 = offs[segP] + sB[segP >> 8] + cntArr[segP];   // end of segP's run
        if (k0 >= end) return;                            // no cell starts here
    }
    int segE = e8[end - 1].x >> 13;
    int kend = offs[segE] + sB[segE >> 8] + cntArr[segE]; // extend thru straddler
    int total = kend - k0;

    float2 a = make_float2(0.f, 0.f);
    int curc = -1;
    const int U = 8;
    int nb = total / U;
    if (nb > 0) {
        int2 e[U];
        #pragma unroll
        for (int u = 0; u < U; u++) e[u] = e8[k0 + u];
        for (int g = 0; g < nb; g++) {
            float2 f[U];
            #pragma unroll
            for (int u = 0; u < U; u++) {
                int sx = e[u].x;
                f[u] = ft2[((size_t)((sx >> 29) * NRAY) + (sx & 8191)) * 64 + lane];
            }
            int2 en[U];
            if (g + 1 < nb) {
                #pragma unroll
                for (int u = 0; u < U; u++) en[u] = e8[k0 + (g + 1) * U + u];
            } else {
                #pragma unroll
                for (int u = 0; u < U; u++) en[u] = e[u];
            }
            #pragma unroll
            for (int u = 0; u < U; u++) {
                int sg = e[u].x >> 13;
                if (sg != curc) {
                    if (curc >= 0) *(float2*)(acc + (size_t)curc * Cc + 2 * lane) = a;
                    curc = sg; a.x = 0.f; a.y = 0.f;
                }
                float ww = __int_as_float(e[u].y);
                a.x = fmaf(ww, f[u].x, a.x);
                a.y = fmaf(ww, f[u].y, a.y);
            }
            #pragma unroll
            for (int u = 0; u < U; u++) e[u] = en[u];
        }
    }
    for (int j = nb * U; j < total; j++) {
        int2 ee = e8[k0 + j];
        int sg = ee.x >> 13;
        if (sg != curc) {
            if (curc >= 0) *(float2*)(acc + (size_t)curc * Cc + 2 * lane) = a;
            curc = sg; a.x = 0.f; a.y = 0.f;
        }
        float ww = __int_as_float(ee.y);
        float2 f = ft2[((size_t)((ee.x >> 29) * NRAY) + (ee.x & 8191)) * 64 + lane];
        a.x = fmaf(ww, f.x, a.x);
        a.y = fmaf(ww, f.y, a.y);
    }
    if (curc >= 0) *(float2*)(acc + (size_t)curc * Cc + 2 * lane) = a;
}

// ---------------------------------------------------------------------------
// Kernel E: finish — normalize + transpose acc[seg][c] -> out[b][c][cell].
// ---------------------------------------------------------------------------
__global__ __launch_bounds__(256) void k_finish(const float* __restrict__ acc,
                                                const int* __restrict__ cntArr,
                                                float* __restrict__ out) {
    __shared__ float res[GT * 132];
    __shared__ float sInv[GT];
    __shared__ int   sC[GT + 1];
    int seg0  = blockIdx.x * GT;
    int b     = seg0 >> 16;
    int cell0 = seg0 & 65535;
    int tid = threadIdx.x;
    if (tid < 64) {
        int n = (tid < GT) ? cntArr[seg0 + tid] : 0;
        int v = n;
        #pragma unroll
        for (int d = 1; d < GT; d <<= 1) {
            int y = __shfl_up(v, d, GT);
            if ((tid & (GT - 1)) >= d) v += y;
        }
        if (tid < GT) {
            sC[tid] = n;
            sInv[tid] = __fdiv_rn(1.0f, __fadd_rn((float)n, 1e-5f));
            if (tid == GT - 1) sC[GT] = v;
        }
    }
    __syncthreads();
    float* ob = out + (size_t)b * Cc * BEV_HW + cell0;
    if (sC[GT] == 0) {                       // all 16 cells empty
        float4 z = {0.f, 0.f, 0.f, 0.f};
        for (int i = tid; i < Cc * GT / 4; i += 256) {
            int q = i & 3, c = i >> 2;
            *(float4*)(ob + (size_t)c * BEV_HW + q * 4) = z;
        }
        return;
    }
    {
        int g0 = tid >> 5, l32 = tid & 31;
        #pragma unroll
        for (int pass = 0; pass < 2; pass++) {
            int g = g0 + pass * 8;
            float4 v;
            if (sC[g] > 0) v = *(const float4*)(acc + (size_t)(seg0 + g) * Cc + 4 * l32);
            else           v = make_float4(0.f, 0.f, 0.f, 0.f);
            *(float4*)(&res[g * 132 + 4 * l32]) = v;
        }
    }
    __syncthreads();
    for (int i = tid; i < Cc * GT / 4; i += 256) {
        int q = i & 3, c = i >> 2;
        float4 v;
        #pragma unroll
        for (int kk = 0; kk < 4; kk++) {
            int g = q * 4 + kk;
            (&v.x)[kk] = __fmul_rn(res[g * 132 + c], sInv[g]);
        }
        *(float4*)(ob + (size_t)c * BEV_HW + q * 4) = v;
    }
}

// ======================= fallback (round-2 proven) ==========================
__global__ __launch_bounds__(256) void k_classifyF(const float* __restrict__ Ki_all,
                                                   const float* __restrict__ db,
                                                   const float* __restrict__ extr,
                                                   int* __restrict__ idxT,
                                                   float* __restrict__ cnt) {
    int gid = blockIdx.x * 256 + threadIdx.x;
    if (gid >= NPTS) return;
    int cell = classify_point(gid, Ki_all, db, extr);
    idxT[gid] = cell;
    if (cell >= 0) {
        int b = gid / (Nc * Dc * HWc);
        atomicAdd(&cnt[b * BEV_HW + cell], 1.0f);
    }
}

__global__ __launch_bounds__(256) void k_scatterF(const float* __restrict__ feat,
                                                  const float* __restrict__ depth,
                                                  const int* __restrict__ idxT,
                                                  float* __restrict__ out) {
    __shared__ float s_dw[HWc];
    __shared__ int   s_idx[HWc];
    int blk = blockIdx.x;
    int bn  = blk / Dc;
    int b   = bn / Nc;
    int tid = threadIdx.x;
    const float* dp = depth + (size_t)blk * HWc;
    const int*   ip = idxT  + (size_t)blk * HWc;
    for (int p = tid; p < HWc; p += 256) { s_dw[p] = dp[p]; s_idx[p] = ip[p]; }
    __syncthreads();
    const float* fb = feat + (size_t)bn * Cc * HWc;
    float*       ob = out  + (size_t)b  * Cc * BEV_HW;
    for (int c = 0; c < Cc; c++) {
        const float* f = fb + (size_t)c * HWc;
        float*       o = ob + (size_t)c * BEV_HW;
        for (int p = tid; p < HWc; p += 256) {
            int cell = s_idx[p];
            if (cell >= 0) atomicAdd(&o[cell], __fmul_rn(f[p], s_dw[p]));
        }
    }
}

__global__ __launch_bounds__(256) void k_normF(float* __restrict__ out,
                                               const float* __restrict__ cnt) {
    int i = blockIdx.x * 256 + threadIdx.x;
    const int total = Bc * Cc * BEV_HW / 4;
    if (i >= total) return;
    int q = i % (BEV_HW / 4);
    int b = i / (Cc * BEV_HW / 4);
    float4 v = ((float4*)out)[i];
    float4 cv = ((const float4*)cnt)[b * (BEV_HW / 4) + q];
    v.x = __fdiv_rn(v.x, __fadd_rn(cv.x, 1e-5f));
    v.y = __fdiv_rn(v.y, __fadd_rn(cv.y, 1e-5f));
    v.z = __fdiv_rn(v.z, __fadd_rn(cv.z, 1e-5f));
    v.w = __fdiv_rn(v.w, __fadd_rn(cv.w, 1e-5f));
    ((float4*)out)[i] = v;
}

// ===========================================================================
extern "C" void kernel_launch(void* const* d_in, const int* in_sizes, int n_in,
                              void* d_out, int out_size, void* d_ws, size_t ws_size,
                              hipStream_t stream) {
    const float* feat  = (const float*)d_in[0];
    const float* depth = (const float*)d_in[1];
    const float* intr  = (const float*)d_in[2];
    const float* extr  = (const float*)d_in[3];
    const int*   imh   = (const int*)d_in[4];
    const int*   imw   = (const int*)d_in[5];
    float* out = (float*)d_out;
    char*  ws  = (char*)d_ws;

    if (ws_size >= (size_t)WS_BIG) {
        int*   cntA = (int*)(ws + OFF_CNT);
        int*   offs = (int*)(ws + OFF_OFFS);
        int*   fill = (int*)(ws + OFF_FILL);
        int*   bsum = (int*)(ws + OFF_BSUM);
        int2*  e8   = (int2*)(ws + OFF_E8);
        float* ft   = (float*)(ws + OFF_FT);
        float* acc  = (float*)(ws + OFF_ACC);

        hipMemsetAsync(cntA, 0, (size_t)NSEG * sizeof(int), stream);
        k_count<<<NPTS / 256, 256, 0, stream>>>(intr, extr, imh, imw, feat, cntA, ft);
        k_scanB<<<NSCANB, 256, 0, stream>>>(cntA, offs, fill, bsum);
        k_fill<<<NPTS / 256, 256, 0, stream>>>(intr, extr, imh, imw, depth, fill, bsum, e8);
        k_gather2<<<GNB, 256, 0, stream>>>((const float2*)ft, e8, cntA, offs, bsum, acc);
        k_finish<<<NTILE, 256, 0, stream>>>(acc, cntA, out);
    } else {
        float* Ki   = (float*)(ws + OFF_KI);
        float* db   = (float*)(ws + OFF_DB);
        int*   idxT = (int*)(ws + OFF_FIDX);
        float* cnt  = (float*)(ws + OFF_FCNT);
        hipMemsetAsync(out, 0, (size_t)out_size * sizeof(float), stream);
        hipMemsetAsync(cnt, 0, (size_t)Bc * BEV_HW * sizeof(float), stream);
        k_setup<<<1, 64, 0, stream>>>(intr, extr, imh, imw, Ki, db);
        k_classifyF<<<(NPTS + 255) / 256, 256, 0, stream>>>(Ki, db, extr, idxT, cnt);
        k_scatterF<<<Bc * Nc * Dc, 256, 0, stream>>>(feat, depth, idxT, out);
        k_normF<<<(Bc * Cc * BEV_HW / 4 + 255) / 256, 256, 0, stream>>>(out, cnt);
    }
}

// Round 16
// 151.110 us; speedup vs baseline: 5.1590x; 1.0927x over previous
//
#include <hip/hip_runtime.h>
#include <hip/hip_bf16.h>

// Problem constants
#define Bc 2
#define Nc 6
#define Cc 128
#define Hc 16
#define Wc 44
#define Dc 64
#define HWc (Hc*Wc)          // 704
#define BNc (Bc*Nc)          // 12
#define NRAY (Nc*HWc)        // 4224
#define NPTS (Bc*Nc*Dc*HWc)  // 540672
#define BEV_W 256
#define BEV_H 256
#define BEV_HW (BEV_W*BEV_H) // 65536
#define NSEG (Bc*BEV_HW)     // 131072
#define GT 16
#define NTILE (NSEG/GT)      // 8192
#define NSCANB 512           // scan blocks (256 segs each)
#define GNB 1056             // gather2 blocks
#define GNW (GNB*4)          // 4224 waves

// ---------------- workspace layout (bytes) ----------------
#define OFF_KI    0                      // fallback only
#define OFF_DB    512                    // fallback only
#define OFF_CNT   1024                   // int cnt[NSEG]      524288
#define OFF_OFFS  (OFF_CNT  + 524288)    // int offs[NSEG]     524288 (block-local excl)
#define OFF_FILL  (OFF_OFFS + 524288)    // int fill[NSEG]     524288
#define OFF_BSUM  (OFF_FILL + 524288)    // int bsum[512]      2048 (raw block sums)
#define OFF_E8    (OFF_BSUM + 4096)      // int2 e8[NPTS]      4325376 {ray|seg<<13, w}
#define OFF_FT    (OFF_E8   + 4325376)   // float ft[B][NRAY][128] 4325376
#define WS_NEED   (OFF_FT   + 4325376)   // ~9.8 MB
#define OFF_ACC   (OFF_FT   + 4325376)   // float acc[NSEG][128] 67108864
#define WS_BIG    (OFF_ACC  + 67108864)  // ~77 MB
#define OFF_FIDX  OFF_E8
#define OFF_FCNT  OFF_CNT

// ---------------------------------------------------------------------------
// numpy-f32-exact setup of Kinv (per bn) and dbins.
// ---------------------------------------------------------------------------
__device__ __forceinline__ void setup_into(int tid, const float* __restrict__ intr,
                                           const int* __restrict__ p_imgh,
                                           const int* __restrict__ p_imgw,
                                           float* Ki, float* db) {
    if (tid < Dc) {
        double v = 1.0 + (double)tid * (59.0 / 63.0);
        db[tid] = (tid == Dc - 1) ? 60.0f : (float)v;   // np.linspace endpoint = stop
    }
    if (tid >= BNc) return;
    double img_h = (double)p_imgh[0];
    double img_w = (double)p_imgw[0];
    double scale_x = (double)Wc / (img_w / 16.0);
    double scale_y = (double)Hc / (img_h / 16.0);
    float rs0 = (float)(16.0 / scale_x);
    float rs1 = (float)(16.0 / scale_y);
    float rs2 = 1.0f;
    const float* K = intr + tid * 9;
    float k0 = __fmul_rn(K[0], rs0), k1 = __fmul_rn(K[1], rs0), k2 = __fmul_rn(K[2], rs0);
    float k3 = __fmul_rn(K[3], rs1), k4 = __fmul_rn(K[4], rs1), k5 = __fmul_rn(K[5], rs1);
    float k6 = __fmul_rn(K[6], rs2), k7 = __fmul_rn(K[7], rs2), k8 = __fmul_rn(K[8], rs2);
    float c0 = __fsub_rn(__fmul_rn(k4,k8), __fmul_rn(k5,k7));
    float c1 = __fsub_rn(__fmul_rn(k3,k8), __fmul_rn(k5,k6));
    float c2 = __fsub_rn(__fmul_rn(k3,k7), __fmul_rn(k4,k6));
    float det = __fadd_rn(__fsub_rn(__fmul_rn(k0,c0), __fmul_rn(k1,c1)), __fmul_rn(k2,c2));
    float* o = Ki + tid * 9;
    o[0] = __fdiv_rn(c0, det);
    o[1] = __fdiv_rn(__fsub_rn(__fmul_rn(k2,k7), __fmul_rn(k1,k8)), det);
    o[2] = __fdiv_rn(__fsub_rn(__fmul_rn(k1,k5), __fmul_rn(k2,k4)), det);
    o[3] = __fdiv_rn(__fsub_rn(__fmul_rn(k5,k6), __fmul_rn(k3,k8)), det);
    o[4] = __fdiv_rn(__fsub_rn(__fmul_rn(k0,k8), __fmul_rn(k2,k6)), det);
    o[5] = __fdiv_rn(__fsub_rn(__fmul_rn(k2,k3), __fmul_rn(k0,k5)), det);
    o[6] = __fdiv_rn(c2, det);
    o[7] = __fdiv_rn(__fsub_rn(__fmul_rn(k1,k6), __fmul_rn(k0,k7)), det);
    o[8] = __fdiv_rn(__fsub_rn(__fmul_rn(k0,k4), __fmul_rn(k1,k3)), det);
}

__global__ void k_setup(const float* __restrict__ intr, const float* __restrict__ extr,
                        const int* __restrict__ p_imgh, const int* __restrict__ p_imgw,
                        float* __restrict__ Ki, float* __restrict__ db) {
    setup_into(threadIdx.x, intr, p_imgh, p_imgw, Ki, db);
}

// ---------------------------------------------------------------------------
// numpy-f32-exact classify: point gid -> BEV cell (or -1)
// ---------------------------------------------------------------------------
__device__ __forceinline__ int classify_point(int gid, const float* Ki_all,
                                              const float* db, const float* extr) {
    int p   = gid % HWc;
    int tmp = gid / HWc;
    int d   = tmp % Dc;
    int bn  = tmp / Dc;
    int w = p % Wc, h = p / Wc;
    float dd = db[d];
    float ud = __fmul_rn((float)w, dd);
    float vd = __fmul_rn((float)h, dd);
    const float* Ki = Ki_all + bn * 9;
    float pcx = fmaf(Ki[2], dd, fmaf(Ki[1], vd, __fmul_rn(Ki[0], ud)));
    float pcy = fmaf(Ki[5], dd, fmaf(Ki[4], vd, __fmul_rn(Ki[3], ud)));
    float pcz = fmaf(Ki[8], dd, fmaf(Ki[7], vd, __fmul_rn(Ki[6], ud)));
    const float* E = extr + bn * 16;
    float px = __fadd_rn(fmaf(E[2],  pcz, fmaf(E[1], pcy, __fmul_rn(E[0], pcx))), E[3]);
    float py = __fadd_rn(fmaf(E[6],  pcz, fmaf(E[5], pcy, __fmul_rn(E[4], pcx))), E[7]);
    float pz = __fadd_rn(fmaf(E[10], pcz, fmaf(E[9], pcy, __fmul_rn(E[8], pcx))), E[11]);
    float fx = __fdiv_rn(__fsub_rn(px, -51.2f), 0.4f);
    float fy = __fdiv_rn(__fsub_rn(py, -51.2f), 0.4f);
    int xi = (int)fx;
    int yi = (int)fy;
    bool valid = (xi >= 0) && (xi < BEV_W) && (yi >= 0) && (yi < BEV_H)
              && (pz >= -5.0f) && (pz <= 3.0f);
    return valid ? (yi * BEV_W + xi) : -1;
}

// ---------------------------------------------------------------------------
// bsum preamble (proven rounds 11/12/15): scan bsum[512] into LDS sB; Etot.
// ---------------------------------------------------------------------------
__device__ __forceinline__ void scan_bsum(int tid, const int* __restrict__ bsum,
                                          int* sB, int* su, int* pEtotS) {
    int2 v2 = ((const int2*)bsum)[tid];      // 512 ints = 256 int2
    int s = v2.x + v2.y;
    su[tid] = s;
    __syncthreads();
    for (int st = 1; st < 256; st <<= 1) {
        int t2 = (tid >= st) ? su[tid - st] : 0;
        __syncthreads();
        su[tid] += t2;
        __syncthreads();
    }
    int base = su[tid] - s;                  // exclusive
    sB[2 * tid]     = base;
    sB[2 * tid + 1] = base + v2.x;
    if (tid == 255) *pEtotS = base + s;
    __syncthreads();
}

// ---------------------------------------------------------------------------
// wave run-length helpers: consecutive lanes (consecutive w) often share a
// cell -> compress runs so only head lanes do the device atomic.
// ---------------------------------------------------------------------------
__device__ __forceinline__ unsigned long long lanemask_le(int lane) {
    return (lane == 63) ? ~0ull : ((1ull << (lane + 1)) - 1ull);
}

// ---------------------------------------------------------------------------
// Kernel A: count (+ fused setup, + fused transpose in first 528 blocks).
// Wave-aggregated: head lane of each equal-seg run adds the run length.
// ---------------------------------------------------------------------------
__global__ __launch_bounds__(256) void k_count(const float* __restrict__ intr,
                                               const float* __restrict__ extr,
                                               const int* __restrict__ p_imgh,
                                               const int* __restrict__ p_imgw,
                                               const float* __restrict__ feat,
                                               int* __restrict__ cntArr,
                                               float* __restrict__ ft) {
    __shared__ float sKi[BNc * 9];
    __shared__ float sDb[Dc];
    __shared__ float buf[Cc * 17];
    int tid = threadIdx.x;
    setup_into(tid, intr, p_imgh, p_imgw, sKi, sDb);
    __syncthreads();
    int gid = blockIdx.x * 256 + tid;      // grid = NPTS/256 exactly
    int cell = classify_point(gid, sKi, sDb, extr);
    {
        int lane = tid & 63;
        int b = gid / (Nc * Dc * HWc);
        int seg = b * BEV_HW + cell;                 // meaningful only if cell>=0
        int key = (cell >= 0) ? seg : -1;
        int pk  = __shfl_up(key, 1);
        bool bnd = (lane == 0) || (key != pk);
        unsigned long long bm = __ballot(bnd);
        if (key >= 0 && bnd) {
            unsigned long long rest = (lane == 63) ? 0ull : (bm >> (lane + 1));
            int runlen = (rest != 0ull) ? __ffsll((long long)rest) : (64 - lane);
            atomicAdd(&cntArr[seg], runlen);
        }
    }
    if (blockIdx.x < BNc * (HWc / 16)) {
        int bn   = blockIdx.x / (HWc / 16);
        int tile = blockIdx.x % (HWc / 16);
        const float* fb = feat + (size_t)bn * Cc * HWc + tile * 16;
        for (int i = tid; i < Cc * 16; i += 256) {
            int c = i >> 4, hw = i & 15;
            buf[c * 17 + hw] = fb[c * HWc + hw];
        }
        __syncthreads();
        float* obt = ft + ((size_t)bn * HWc + tile * 16) * Cc;
        for (int i = tid; i < 16 * Cc; i += 256) {
            int r = i >> 7, ch = i & 127;
            obt[(size_t)r * Cc + ch] = buf[ch * 17 + r];
        }
    }
}

// ---------------------------------------------------------------------------
// Kernel B: parallel scan — 512 blocks x 256 (proven round 15).
// ---------------------------------------------------------------------------
__global__ __launch_bounds__(256) void k_scanB(const int* __restrict__ cntArr,
                                               int* __restrict__ offs,
                                               int* __restrict__ fill,
                                               int* __restrict__ bsum) {
    __shared__ int su[256];
    int tid = threadIdx.x;
    int g = blockIdx.x * 256 + tid;
    int v = cntArr[g];
    su[tid] = v;
    __syncthreads();
    for (int st = 1; st < 256; st <<= 1) {
        int t2 = (tid >= st) ? su[tid - st] : 0;
        __syncthreads();
        su[tid] += t2;
        __syncthreads();
    }
    int e = su[tid] - v;
    offs[g] = e;
    fill[g] = e;
    if (tid == 255) bsum[blockIdx.x] = su[255];
}

// ---------------------------------------------------------------------------
// Kernel C: fill packed entries {ray | seg<<13, weight-bits}.
// Wave-aggregated: head reserves runlen slots with ONE returning atomic;
// members write e8 at base+rank -> coalesced bursts.
// ---------------------------------------------------------------------------
__global__ __launch_bounds__(256) void k_fill(const float* __restrict__ intr,
                                              const float* __restrict__ extr,
                                              const int* __restrict__ p_imgh,
                                              const int* __restrict__ p_imgw,
                                              const float* __restrict__ depth,
                                              int* __restrict__ fill,
                                              const int* __restrict__ bsum,
                                              int2* __restrict__ e8) {
    __shared__ float sKi[BNc * 9];
    __shared__ float sDb[Dc];
    __shared__ int   sB[NSCANB];
    __shared__ int   su[256];
    __shared__ int   sEtot;
    int tid = threadIdx.x;
    setup_into(tid, intr, p_imgh, p_imgw, sKi, sDb);
    scan_bsum(tid, bsum, sB, su, &sEtot);
    int gid = blockIdx.x * 256 + tid;
    int cell = classify_point(gid, sKi, sDb, extr);
    int lane = tid & 63;
    int bnum = gid / (Nc * Dc * HWc);
    int seg = bnum * BEV_HW + cell;
    int key = (cell >= 0) ? seg : -1;
    int pk  = __shfl_up(key, 1);
    bool bnd = (lane == 0) || (key != pk);
    unsigned long long bm = __ballot(bnd);
    int base = 0;
    if (key >= 0 && bnd) {
        unsigned long long rest = (lane == 63) ? 0ull : (bm >> (lane + 1));
        int runlen = (rest != 0ull) ? __ffsll((long long)rest) : (64 - lane);
        base = atomicAdd(&fill[seg], runlen) + sB[seg >> 8];
    }
    // broadcast base from my run's head lane
    int headLane = 63 - __clzll(bm & lanemask_le(lane));
    int myBase = __shfl(base, headLane);
    if (key >= 0) {
        int p   = gid % HWc;
        int bn  = gid / (Dc * HWc);
        int ray = (bn % Nc) * HWc + p;
        e8[myBase + (lane - headLane)] = make_int2(ray | (seg << 13),
                                                   __float_as_int(depth[gid]));
    }
}

// ---------------------------------------------------------------------------
// Kernel D: entry-parallel ownership gather -> acc[seg][128] (proven r15).
// ---------------------------------------------------------------------------
__global__ __launch_bounds__(256) void k_gather2(const float2* __restrict__ ft2,
                                                 const int2* __restrict__ e8,
                                                 const int* __restrict__ cntArr,
                                                 const int* __restrict__ offs,
                                                 const int* __restrict__ bsum,
                                                 float* __restrict__ acc) {
    __shared__ int sB[NSCANB];
    __shared__ int su[256];
    __shared__ int sEtot;
    int tid = threadIdx.x;
    scan_bsum(tid, bsum, sB, su, &sEtot);
    int Etot = sEtot;
    int wid  = blockIdx.x * 4 + (tid >> 6);
    int lane = tid & 63;
    int WCH  = (Etot + GNW - 1) / GNW;
    if (WCH <= 0) return;
    int start = wid * WCH;
    if (start >= Etot) return;
    int end = start + WCH; if (end > Etot) end = Etot;
    int k0 = 0;
    if (start > 0) {
        int segP = e8[start - 1].x >> 13;
        k0 = offs[segP] + sB[segP >> 8] + cntArr[segP];   // end of segP's run
        if (k0 >= end) return;                            // no cell starts here
    }
    int segE = e8[end - 1].x >> 13;
    int kend = offs[segE] + sB[segE >> 8] + cntArr[segE]; // extend thru straddler
    int total = kend - k0;

    float2 a = make_float2(0.f, 0.f);
    int curc = -1;
    const int U = 8;
    int nb = total / U;
    if (nb > 0) {
        int2 e[U];
        #pragma unroll
        for (int u = 0; u < U; u++) e[u] = e8[k0 + u];
        for (int g = 0; g < nb; g++) {
            float2 f[U];
            #pragma unroll
            for (int u = 0; u < U; u++) {
                int sx = e[u].x;
                f[u] = ft2[((size_t)((sx >> 29) * NRAY) + (sx & 8191)) * 64 + lane];
            }
            int2 en[U];
            if (g + 1 < nb) {
                #pragma unroll
                for (int u = 0; u < U; u++) en[u] = e8[k0 + (g + 1) * U + u];
            } else {
                #pragma unroll
                for (int u = 0; u < U; u++) en[u] = e[u];
            }
            #pragma unroll
            for (int u = 0; u < U; u++) {
                int sg = e[u].x >> 13;
                if (sg != curc) {
                    if (curc >= 0) *(float2*)(acc + (size_t)curc * Cc + 2 * lane) = a;
                    curc = sg; a.x = 0.f; a.y = 0.f;
                }
                float ww = __int_as_float(e[u].y);
                a.x = fmaf(ww, f[u].x, a.x);
                a.y = fmaf(ww, f[u].y, a.y);
            }
            #pragma unroll
            for (int u = 0; u < U; u++) e[u] = en[u];
        }
    }
    for (int j = nb * U; j < total; j++) {
        int2 ee = e8[k0 + j];
        int sg = ee.x >> 13;
        if (sg != curc) {
            if (curc >= 0) *(float2*)(acc + (size_t)curc * Cc + 2 * lane) = a;
            curc = sg; a.x = 0.f; a.y = 0.f;
        }
        float ww = __int_as_float(ee.y);
        float2 f = ft2[((size_t)((ee.x >> 29) * NRAY) + (ee.x & 8191)) * 64 + lane];
        a.x = fmaf(ww, f.x, a.x);
        a.y = fmaf(ww, f.y, a.y);
    }
    if (curc >= 0) *(float2*)(acc + (size_t)curc * Cc + 2 * lane) = a;
}

// ---------------------------------------------------------------------------
// Kernel E: finish — normalize + transpose acc[seg][c] -> out[b][c][cell].
// ---------------------------------------------------------------------------
__global__ __launch_bounds__(256) void k_finish(const float* __restrict__ acc,
                                                const int* __restrict__ cntArr,
                                                float* __restrict__ out) {
    __shared__ float res[GT * 132];
    __shared__ float sInv[GT];
    __shared__ int   sC[GT + 1];
    int seg0  = blockIdx.x * GT;
    int b     = seg0 >> 16;
    int cell0 = seg0 & 65535;
    int tid = threadIdx.x;
    if (tid < 64) {
        int n = (tid < GT) ? cntArr[seg0 + tid] : 0;
        int v = n;
        #pragma unroll
        for (int d = 1; d < GT; d <<= 1) {
            int y = __shfl_up(v, d, GT);
            if ((tid & (GT - 1)) >= d) v += y;
        }
        if (tid < GT) {
            sC[tid] = n;
            sInv[tid] = __fdiv_rn(1.0f, __fadd_rn((float)n, 1e-5f));
            if (tid == GT - 1) sC[GT] = v;
        }
    }
    __syncthreads();
    float* ob = out + (size_t)b * Cc * BEV_HW + cell0;
    if (sC[GT] == 0) {                       // all 16 cells empty
        float4 z = {0.f, 0.f, 0.f, 0.f};
        for (int i = tid; i < Cc * GT / 4; i += 256) {
            int q = i & 3, c = i >> 2;
            *(float4*)(ob + (size_t)c * BEV_HW + q * 4) = z;
        }
        return;
    }
    {
        int g0 = tid >> 5, l32 = tid & 31;
        #pragma unroll
        for (int pass = 0; pass < 2; pass++) {
            int g = g0 + pass * 8;
            float4 v;
            if (sC[g] > 0) v = *(const float4*)(acc + (size_t)(seg0 + g) * Cc + 4 * l32);
            else           v = make_float4(0.f, 0.f, 0.f, 0.f);
            *(float4*)(&res[g * 132 + 4 * l32]) = v;
        }
    }
    __syncthreads();
    for (int i = tid; i < Cc * GT / 4; i += 256) {
        int q = i & 3, c = i >> 2;
        float4 v;
        #pragma unroll
        for (int kk = 0; kk < 4; kk++) {
            int g = q * 4 + kk;
            (&v.x)[kk] = __fmul_rn(res[g * 132 + c], sInv[g]);
        }
        *(float4*)(ob + (size_t)c * BEV_HW + q * 4) = v;
    }
}

// ======================= fallback (round-2 proven) ==========================
__global__ __launch_bounds__(256) void k_classifyF(const float* __restrict__ Ki_all,
                                                   const float* __restrict__ db,
                                                   const float* __restrict__ extr,
                                                   int* __restrict__ idxT,
                                                   float* __restrict__ cnt) {
    int gid = blockIdx.x * 256 + threadIdx.x;
    if (gid >= NPTS) return;
    int cell = classify_point(gid, Ki_all, db, extr);
    idxT[gid] = cell;
    if (cell >= 0) {
        int b = gid / (Nc * Dc * HWc);
        atomicAdd(&cnt[b * BEV_HW + cell], 1.0f);
    }
}

__global__ __launch_bounds__(256) void k_scatterF(const float* __restrict__ feat,
                                                  const float* __restrict__ depth,
                                                  const int* __restrict__ idxT,
                                                  float* __restrict__ out) {
    __shared__ float s_dw[HWc];
    __shared__ int   s_idx[HWc];
    int blk = blockIdx.x;
    int bn  = blk / Dc;
    int b   = bn / Nc;
    int tid = threadIdx.x;
    const float* dp = depth + (size_t)blk * HWc;
    const int*   ip = idxT  + (size_t)blk * HWc;
    for (int p = tid; p < HWc; p += 256) { s_dw[p] = dp[p]; s_idx[p] = ip[p]; }
    __syncthreads();
    const float* fb = feat + (size_t)bn * Cc * HWc;
    float*       ob = out  + (size_t)b  * Cc * BEV_HW;
    for (int c = 0; c < Cc; c++) {
        const float* f = fb + (size_t)c * HWc;
        float*       o = ob + (size_t)c * BEV_HW;
        for (int p = tid; p < HWc; p += 256) {
            int cell = s_idx[p];
            if (cell >= 0) atomicAdd(&o[cell], __fmul_rn(f[p], s_dw[p]));
        }
    }
}

__global__ __launch_bounds__(256) void k_normF(float* __restrict__ out,
                                               const float* __restrict__ cnt) {
    int i = blockIdx.x * 256 + threadIdx.x;
    const int total = Bc * Cc * BEV_HW / 4;
    if (i >= total) return;
    int q = i % (BEV_HW / 4);
    int b = i / (Cc * BEV_HW / 4);
    float4 v = ((float4*)out)[i];
    float4 cv = ((const float4*)cnt)[b * (BEV_HW / 4) + q];
    v.x = __fdiv_rn(v.x, __fadd_rn(cv.x, 1e-5f));
    v.y = __fdiv_rn(v.y, __fadd_rn(cv.y, 1e-5f));
    v.z = __fdiv_rn(v.z, __fadd_rn(cv.z, 1e-5f));
    v.w = __fdiv_rn(v.w, __fadd_rn(cv.w, 1e-5f));
    ((float4*)out)[i] = v;
}

// ===========================================================================
extern "C" void kernel_launch(void* const* d_in, const int* in_sizes, int n_in,
                              void* d_out, int out_size, void* d_ws, size_t ws_size,
                              hipStream_t stream) {
    const float* feat  = (const float*)d_in[0];
    const float* depth = (const float*)d_in[1];
    const float* intr  = (const float*)d_in[2];
    const float* extr  = (const float*)d_in[3];
    const int*   imh   = (const int*)d_in[4];
    const int*   imw   = (const int*)d_in[5];
    float* out = (float*)d_out;
    char*  ws  = (char*)d_ws;

    if (ws_size >= (size_t)WS_BIG) {
        int*   cntA = (int*)(ws + OFF_CNT);
        int*   offs = (int*)(ws + OFF_OFFS);
        int*   fill = (int*)(ws + OFF_FILL);
        int*   bsum = (int*)(ws + OFF_BSUM);
        int2*  e8   = (int2*)(ws + OFF_E8);
        float* ft   = (float*)(ws + OFF_FT);
        float* acc  = (float*)(ws + OFF_ACC);

        hipMemsetAsync(cntA, 0, (size_t)NSEG * sizeof(int), stream);
        k_count<<<NPTS / 256, 256, 0, stream>>>(intr, extr, imh, imw, feat, cntA, ft);
        k_scanB<<<NSCANB, 256, 0, stream>>>(cntA, offs, fill, bsum);
        k_fill<<<NPTS / 256, 256, 0, stream>>>(intr, extr, imh, imw, depth, fill, bsum, e8);
        k_gather2<<<GNB, 256, 0, stream>>>((const float2*)ft, e8, cntA, offs, bsum, acc);
        k_finish<<<NTILE, 256, 0, stream>>>(acc, cntA, out);
    } else {
        float* Ki   = (float*)(ws + OFF_KI);
        float* db   = (float*)(ws + OFF_DB);
        int*   idxT = (int*)(ws + OFF_FIDX);
        float* cnt  = (float*)(ws + OFF_FCNT);
        hipMemsetAsync(out, 0, (size_t)out_size * sizeof(float), stream);
        hipMemsetAsync(cnt, 0, (size_t)Bc * BEV_HW * sizeof(float), stream);
        k_setup<<<1, 64, 0, stream>>>(intr, extr, imh, imw, Ki, db);
        k_classifyF<<<(NPTS + 255) / 256, 256, 0, stream>>>(Ki, db, extr, idxT, cnt);
        k_scatterF<<<Bc * Nc * Dc, 256, 0, stream>>>(feat, depth, idxT, out);
        k_normF<<<(Bc * Cc * BEV_HW / 4 + 255) / 256, 256, 0, stream>>>(out, cnt);
    }
}